// Round 15
// baseline (1691.413 us; speedup 1.0000x reference)
//
#include <hip/hip_runtime.h>
#include <hip/hip_bf16.h>
#include <stdint.h>

#define LNUM 6
#define BB 8
#define TT 1024
#define CC 768
#define HH 12
#define HDIM 64
#define DFF 3072
#define VV 512
#define MM (BB*TT)
#define QKREG ((size_t)BB*HH*TT*64)

typedef __bf16 bf16x8 __attribute__((ext_vector_type(8)));
typedef float f32x4 __attribute__((ext_vector_type(4)));

__device__ __forceinline__ uint16_t f2b(float f) {
  uint32_t u = __float_as_uint(f);
  u += 0x7FFFu + ((u >> 16) & 1u);
  return (uint16_t)(u >> 16);
}

__device__ __forceinline__ float b2f(uint16_t u) {
  return __uint_as_float((uint32_t)u << 16);
}

__device__ __forceinline__ void gld16(const uint16_t* g, uint16_t* l) {
  __builtin_amdgcn_global_load_lds(
      (const __attribute__((address_space(1))) uint32_t*)g,
      (__attribute__((address_space(3))) uint32_t*)l, 16, 0, 0);
}

__device__ __forceinline__ f32x4 mfma16(bf16x8 a, bf16x8 b, f32x4 c) {
  return __builtin_amdgcn_mfma_f32_16x16x32_bf16(a, b, c, 0, 0, 0);
}

// ---------------- convert f32 -> bf16 ----------------
__global__ __launch_bounds__(256) void cvt4_k(const float* __restrict__ in,
                                              uint16_t* __restrict__ out, int n4) {
  const int gid = blockIdx.x * 256 + threadIdx.x;
  if (gid >= n4) return;
  const float4 v = ((const float4*)in)[gid];
  ushort4 w; w.x = f2b(v.x); w.y = f2b(v.y); w.z = f2b(v.z); w.w = f2b(v.w);
  ((ushort4*)out)[gid] = w;
}

// ---------------- embedding: x(bf16) = tok_emb[idx] + pos_emb ----------------
__global__ __launch_bounds__(256) void embed_k(const int* __restrict__ idx,
                                               const float* __restrict__ tok,
                                               const float* __restrict__ pos,
                                               uint16_t* __restrict__ x) {
  const int gid = blockIdx.x * 256 + threadIdx.x;
  const int row = gid / (CC / 4), c4 = gid % (CC / 4);
  const int t = row & (TT - 1);
  const int tkn = idx[row];
  const float4 a = ((const float4*)(tok + (size_t)tkn * CC))[c4];
  const float4 q = ((const float4*)(pos + (size_t)t * CC))[c4];
  ushort4 w;
  w.x = f2b(a.x + q.x); w.y = f2b(a.y + q.y);
  w.z = f2b(a.z + q.z); w.w = f2b(a.w + q.w);
  ((ushort4*)(x + (size_t)row * CC))[c4] = w;
}

// ---------------- layernorm: bf16 x in -> bf16 out ----------------
__global__ __launch_bounds__(256) void ln_k(const uint16_t* __restrict__ x,
                                            const float* __restrict__ gamma,
                                            const float* __restrict__ beta,
                                            uint16_t* __restrict__ o) {
  const int lane = threadIdx.x & 63, wid = threadIdx.x >> 6;
  const int row = blockIdx.x * 4 + wid;
  const ushort4* xr = (const ushort4*)(x + (size_t)row * CC);
  float4 v[3]; float s = 0.f, sq = 0.f;
#pragma unroll
  for (int i = 0; i < 3; ++i) {
    const ushort4 u = xr[lane + i * 64];
    v[i] = make_float4(b2f(u.x), b2f(u.y), b2f(u.z), b2f(u.w));
    s += v[i].x + v[i].y + v[i].z + v[i].w;
    sq += v[i].x * v[i].x + v[i].y * v[i].y + v[i].z * v[i].z + v[i].w * v[i].w;
  }
#pragma unroll
  for (int m = 1; m < 64; m <<= 1) { s += __shfl_xor(s, m, 64); sq += __shfl_xor(sq, m, 64); }
  const float mu = s * (1.f / 768.f);
  const float rstd = rsqrtf(sq * (1.f / 768.f) - mu * mu + 1e-5f);
  ushort4* orow = (ushort4*)(o + (size_t)row * CC);
#pragma unroll
  for (int i = 0; i < 3; ++i) {
    const int c4 = lane + i * 64;
    const float4 gg = ((const float4*)gamma)[c4];
    const float4 bb = ((const float4*)beta)[c4];
    ushort4 w;
    w.x = f2b((v[i].x - mu) * rstd * gg.x + bb.x);
    w.y = f2b((v[i].y - mu) * rstd * gg.y + bb.y);
    w.z = f2b((v[i].z - mu) * rstd * gg.z + bb.z);
    w.w = f2b((v[i].w - mu) * rstd * gg.w + bb.w);
    orow[c4] = w;
  }
}

// --- layernorm + NP bf16-partial reduce: x(bf16) += sum(p_j); o = LN(x) ---
template <int NP>
__global__ __launch_bounds__(256) void lnrb_k(uint16_t* __restrict__ x,
                                              const uint16_t* __restrict__ pp,
                                              const float* __restrict__ gamma,
                                              const float* __restrict__ beta,
                                              uint16_t* __restrict__ o) {
  const int lane = threadIdx.x & 63, wid = threadIdx.x >> 6;
  const int row = blockIdx.x * 4 + wid;
  ushort4* xr = (ushort4*)(x + (size_t)row * CC);
  float4 v[3]; float s = 0.f, sq = 0.f;
#pragma unroll
  for (int i = 0; i < 3; ++i) {
    const int c4 = lane + i * 64;
    const ushort4 u = xr[c4];
    float4 a = make_float4(b2f(u.x), b2f(u.y), b2f(u.z), b2f(u.w));
#pragma unroll
    for (int j = 0; j < NP; ++j) {
      const ushort4 q =
          ((const ushort4*)(pp + (size_t)j * MM * CC + (size_t)row * CC))[c4];
      a.x += b2f(q.x); a.y += b2f(q.y); a.z += b2f(q.z); a.w += b2f(q.w);
    }
    ushort4 w;
    w.x = f2b(a.x); w.y = f2b(a.y); w.z = f2b(a.z); w.w = f2b(a.w);
    xr[c4] = w;
    v[i] = a;
    s += a.x + a.y + a.z + a.w;
    sq += a.x * a.x + a.y * a.y + a.z * a.z + a.w * a.w;
  }
#pragma unroll
  for (int m = 1; m < 64; m <<= 1) { s += __shfl_xor(s, m, 64); sq += __shfl_xor(sq, m, 64); }
  const float mu = s * (1.f / 768.f);
  const float rstd = rsqrtf(sq * (1.f / 768.f) - mu * mu + 1e-5f);
  ushort4* orow = (ushort4*)(o + (size_t)row * CC);
#pragma unroll
  for (int i = 0; i < 3; ++i) {
    const int c4 = lane + i * 64;
    const float4 gg = ((const float4*)gamma)[c4];
    const float4 bb = ((const float4*)beta)[c4];
    ushort4 w;
    w.x = f2b((v[i].x - mu) * rstd * gg.x + bb.x);
    w.y = f2b((v[i].y - mu) * rstd * gg.y + bb.y);
    w.z = f2b((v[i].z - mu) * rstd * gg.z + bb.z);
    w.w = f2b((v[i].w - mu) * rstd * gg.w + bb.w);
    orow[c4] = w;
  }
}

// ------- all-weights transpose+convert v2: 64(k)x32(n) tiles, 128B writes -------
__global__ __launch_bounds__(256) void tca_k(const float* __restrict__ Wq,
                                             const float* __restrict__ Wp,
                                             const float* __restrict__ W1p,
                                             const float* __restrict__ W2p,
                                             uint16_t* __restrict__ dq,
                                             uint16_t* __restrict__ dp,
                                             uint16_t* __restrict__ d1,
                                             uint16_t* __restrict__ d2) {
  __shared__ float tile[64][33];
  const int b = blockIdx.x;
  const int l = b / 3456;
  int r = b - l * 3456;
  const float* src; uint16_t* dst; int K, N, kt, nt;
  if (r < 864) {
    K = CC; N = 3 * CC;
    src = Wq + (size_t)l * CC * 3 * CC; dst = dq + (size_t)l * CC * 3 * CC;
    kt = r / 72; nt = r % 72;
  } else if (r < 1152) {
    r -= 864; K = CC; N = CC;
    src = Wp + (size_t)l * CC * CC; dst = dp + (size_t)l * CC * CC;
    kt = r / 24; nt = r % 24;
  } else if (r < 2304) {
    r -= 1152; K = CC; N = DFF;
    src = W1p + (size_t)l * CC * DFF; dst = d1 + (size_t)l * CC * DFF;
    kt = r / 96; nt = r % 96;
  } else {
    r -= 2304; K = DFF; N = CC;
    src = W2p + (size_t)l * DFF * CC; dst = d2 + (size_t)l * DFF * CC;
    kt = r / 24; nt = r % 24;
  }
  const int kb = kt * 64, nb = nt * 32;
  const int tx = threadIdx.x & 31, ty = threadIdx.x >> 5;
#pragma unroll
  for (int i = 0; i < 64; i += 8)
    tile[ty + i][tx] = src[(size_t)(kb + ty + i) * N + nb + tx];
  __syncthreads();
#pragma unroll
  for (int i = 0; i < 32; i += 8) {
    const int n = ty + i;
    const int k2 = tx * 2;
    const uint32_t w = (uint32_t)f2b(tile[k2][n]) | ((uint32_t)f2b(tile[k2 + 1][n]) << 16);
    *(uint32_t*)(dst + (size_t)(nb + n) * K + kb + k2) = w;
  }
}

// ---- 128x128 GEMM, BK=64, LDS double-buffer, ONE barrier/tile (T3 2-phase) ----
// Staging for tile t+1 is issued at the TOP of tile t (before ds_read+MFMA),
// so the barrier's implicit vmcnt(0) drain waits on loads issued ~a full
// compute-phase earlier. WAR: barrier at end of t-1 retires all reads of
// buf[t+1&1] before tile t stores to it. Chunk-swizzle as before (rule 21).
// EPI: 1 = f32 store; 2 = bias+GELU -> bf16; 5 = qkv split; 8 = bf16 partials (+bias kp0)
template <int EPI>
__global__ __launch_bounds__(256) void gemm_k(const uint16_t* __restrict__ A,
                                              const uint16_t* __restrict__ Bt,
                                              int N, int K,
                                              const float* __restrict__ bias,
                                              uint16_t* __restrict__ outb,
                                              float* __restrict__ outf) {
  __shared__ __align__(16) uint16_t As[2][128 * 64];
  __shared__ __align__(16) uint16_t Bs[2][128 * 64];
  const int tid = threadIdx.x;
  const int lane = tid & 63, wid = tid >> 6;
  const int wm = wid >> 1, wn = wid & 1;
  const int bm = blockIdx.x * 128, bn = blockIdx.y * 128;
  const int kp = blockIdx.z;
  const int Ksub = K / (int)gridDim.z;
  const int k0b = kp * Ksub;
  const int nkt = Ksub >> 6;
  const int srow = tid >> 3;
  const int swz = (tid & 7) ^ (srow & 7);
  const uint16_t* gA0 = A + (size_t)(bm + srow) * K + k0b + swz * 8;
  const uint16_t* gB0 = Bt + (size_t)(bn + srow) * K + k0b + swz * 8;
  const size_t qs = (size_t)32 * K;
  const int l15 = lane & 15, lhi = lane >> 4;
  int aof[2][4], bof[2][4];
#pragma unroll
  for (int kk = 0; kk < 2; ++kk)
#pragma unroll
    for (int i = 0; i < 4; ++i) {
      const int sw = ((kk * 4 + lhi) ^ (l15 & 7)) * 16;
      aof[kk][i] = (wm * 64 + i * 16 + l15) * 128 + sw;
      bof[kk][i] = (wn * 64 + i * 16 + l15) * 128 + sw;
    }
  f32x4 acc[4][4] = {};
  // prologue: stage tile 0 -> buf 0
#pragma unroll
  for (int q = 0; q < 4; ++q) {
    gld16(gA0 + q * qs, &As[0][q * 2048 + tid * 8]);
    gld16(gB0 + q * qs, &Bs[0][q * 2048 + tid * 8]);
  }
  __syncthreads();
  for (int t = 0; t < nkt; ++t) {
    const int cur = t & 1;
    if (t + 1 < nkt) {  // issue next-tile staging FIRST (latency hides under MFMA)
      const int ko = (t + 1) * 64;
      const int nb = cur ^ 1;
#pragma unroll
      for (int q = 0; q < 4; ++q) {
        gld16(gA0 + q * qs + ko, &As[nb][q * 2048 + tid * 8]);
        gld16(gB0 + q * qs + ko, &Bs[nb][q * 2048 + tid * 8]);
      }
    }
    const char* Ab = (const char*)As[cur];
    const char* Bb = (const char*)Bs[cur];
#pragma unroll
    for (int kk = 0; kk < 2; ++kk) {
      bf16x8 a[4], b[4];
#pragma unroll
      for (int i = 0; i < 4; ++i) {
        a[i] = *(const bf16x8*)(Ab + aof[kk][i]);
        b[i] = *(const bf16x8*)(Bb + bof[kk][i]);
      }
#pragma unroll
      for (int i = 0; i < 4; ++i)
#pragma unroll
        for (int j = 0; j < 4; ++j)
          acc[i][j] = mfma16(a[i], b[j], acc[i][j]);
    }
    __syncthreads();   // one barrier/tile: drains next-tile staging + read fence
  }
#pragma unroll
  for (int i = 0; i < 4; ++i) {
    const int m0 = bm + wm * 64 + i * 16 + (lhi << 2);
#pragma unroll
    for (int j = 0; j < 4; ++j) {
      const int n = bn + wn * 64 + j * 16 + l15;
      if constexpr (EPI == 5) {
        const int sec = n / CC;
        const int rn = n - sec * CC;
        const int hh = rn >> 6, d = rn & 63;
        const int b = m0 >> 10, t0 = m0 & 1023;
        if (sec == 2) {
          ushort4 w;
          w.x = f2b(acc[i][j][0]); w.y = f2b(acc[i][j][1]);
          w.z = f2b(acc[i][j][2]); w.w = f2b(acc[i][j][3]);
          *(ushort4*)(outb + 2 * QKREG + ((size_t)(b * HH + hh) * 64 + d) * TT + t0) = w;
        } else {
          uint16_t* dst = outb + (size_t)sec * QKREG + ((size_t)(b * HH + hh) * TT + t0) * 64 + d;
#pragma unroll
          for (int rr = 0; rr < 4; ++rr) dst[(size_t)rr * 64] = f2b(acc[i][j][rr]);
        }
      } else if constexpr (EPI == 8) {
        uint16_t* pdst = outb + (size_t)kp * ((size_t)MM * N);
        const float bb = (kp == 0 && bias) ? bias[n] : 0.f;
#pragma unroll
        for (int rr = 0; rr < 4; ++rr)
          pdst[(size_t)(m0 + rr) * N + n] = f2b(acc[i][j][rr] + bb);
      } else {
#pragma unroll
        for (int rr = 0; rr < 4; ++rr) {
          const size_t o = (size_t)(m0 + rr) * N + n;
          const float v = acc[i][j][rr];
          if constexpr (EPI == 1) {
            outf[o] = v;
          } else if constexpr (EPI == 2) {
            float t = v + bias[n];
            t = 0.5f * t * (1.0f + erff(t * 0.70710678118654752f));
            outb[o] = f2b(t);
          }
        }
      }
    }
  }
}

// ---- fused causal flash attention: QBLK=128 (8 waves), dbuf K/V, 1 barrier/tile ----
__global__ __launch_bounds__(512) void attn_k(const uint16_t* __restrict__ qkvh,
                                              uint16_t* __restrict__ ao) {
  __shared__ __align__(16) uint16_t Ks[2][64 * 64], Vs[2][64 * 64];
  __shared__ __align__(16) uint16_t Ps[8][16 * 64];
  const int tid = threadIdx.x, lane = tid & 63, wid = tid >> 6;
  const int p = (TT / 128 - 1) - blockIdx.x / (BB * HH);
  const int bh = blockIdx.x % (BB * HH);
  const uint16_t* qb = qkvh + (size_t)bh * (TT * 64);
  const uint16_t* kb = qkvh + QKREG + (size_t)bh * (TT * 64);
  const uint16_t* vb = qkvh + 2 * QKREG + (size_t)bh * ((size_t)64 * TT);
  const int l15 = lane & 15, lhi = lane >> 4;
  bf16x8 qf[2];
  {
    const uint16_t* qr = qb + (size_t)(p * 128 + wid * 16 + l15) * 64 + lhi * 8;
    qf[0] = *(const bf16x8*)qr;
    qf[1] = *(const bf16x8*)(qr + 32);
  }
  const int r0 = tid >> 3;
  const int cb0 = (tid & 7) * 16;
  const int ph0 = r0 * 128 + (cb0 ^ ((r0 & 7) << 4));

  uint4 kr0, vr0;
  kr0 = *(const uint4*)(kb + (size_t)r0 * 64 + cb0 / 2);
  vr0 = *(const uint4*)(vb + (size_t)r0 * TT + cb0 / 2);
  *(uint4*)((char*)Ks[0] + ph0) = kr0;
  *(uint4*)((char*)Vs[0] + ph0) = vr0;

  f32x4 oacc[4] = {};
  float mrun[4] = {-INFINITY, -INFINITY, -INFINITY, -INFINITY};
  float lrun[4] = {0.f, 0.f, 0.f, 0.f};
  char* pb = (char*)Ps[wid];
  const int jmax = 2 * p + 1;
  const int qgmin = p * 128 + wid * 16;

  for (int j = 0; j <= jmax; ++j) {
    const int cur = j & 1;
    const bool more = (j < jmax);
    __syncthreads();
    if (more) {
      const int jn = (j + 1) * 64;
      kr0 = *(const uint4*)(kb + (size_t)(jn + r0) * 64 + cb0 / 2);
      vr0 = *(const uint4*)(vb + (size_t)r0 * TT + jn + cb0 / 2);
    }
    const char* Kb = (const char*)Ks[cur];
    const char* Vb = (const char*)Vs[cur];
    f32x4 s4[4] = {};
    __builtin_amdgcn_s_setprio(1);
#pragma unroll
    for (int kk = 0; kk < 2; ++kk) {
      const int cbyte = kk * 64 + lhi * 16;
#pragma unroll
      for (int nt = 0; nt < 4; ++nt) {
        const int krow = nt * 16 + l15;
        const bf16x8 kf = *(const bf16x8*)(Kb + krow * 128 + (cbyte ^ ((krow & 7) << 4)));
        s4[nt] = mfma16(qf[kk], kf, s4[nt]);
      }
    }
    __builtin_amdgcn_s_setprio(0);
    const bool diag = (j * 64 + 63) > qgmin;
    float alpha[4];
#pragma unroll
    for (int r = 0; r < 4; ++r) {
      const int qg = qgmin + (lhi << 2) + r;
      float mx = -INFINITY;
#pragma unroll
      for (int nt = 0; nt < 4; ++nt) {
        float v = s4[nt][r] * 0.125f;
        if (diag && (j * 64 + nt * 16 + l15) > qg) v = -INFINITY;
        s4[nt][r] = v;
        mx = fmaxf(mx, v);
      }
#pragma unroll
      for (int m = 1; m < 16; m <<= 1) mx = fmaxf(mx, __shfl_xor(mx, m, 16));
      const float mnew = fmaxf(mrun[r], mx);
      alpha[r] = __expf(mrun[r] - mnew);
      float ps = 0.f;
#pragma unroll
      for (int nt = 0; nt < 4; ++nt) {
        const float pp = __expf(s4[nt][r] - mnew);
        s4[nt][r] = pp;
        ps += pp;
      }
#pragma unroll
      for (int m = 1; m < 16; m <<= 1) ps += __shfl_xor(ps, m, 16);
      lrun[r] = lrun[r] * alpha[r] + ps;
      mrun[r] = mnew;
    }
#pragma unroll
    for (int dt = 0; dt < 4; ++dt)
#pragma unroll
      for (int r = 0; r < 4; ++r) oacc[dt][r] *= alpha[r];
#pragma unroll
    for (int r = 0; r < 4; ++r) {
      const int prow = (lhi << 2) + r;
      const int swp = (prow & 7) << 4;
#pragma unroll
      for (int nt = 0; nt < 4; ++nt) {
        const int cb = (nt * 16 + l15) * 2;
        *(uint16_t*)(pb + prow * 128 + (cb ^ swp)) = f2b(s4[nt][r]);
      }
    }
    __builtin_amdgcn_s_setprio(1);
#pragma unroll
    for (int kk = 0; kk < 2; ++kk) {
      const int cbyte = kk * 64 + lhi * 16;
      const bf16x8 pf = *(const bf16x8*)(pb + l15 * 128 + (cbyte ^ ((l15 & 7) << 4)));
#pragma unroll
      for (int dt = 0; dt < 4; ++dt) {
        const int vrow = dt * 16 + l15;
        const bf16x8 vf = *(const bf16x8*)(Vb + vrow * 128 + (cbyte ^ ((vrow & 7) << 4)));
        oacc[dt] = mfma16(pf, vf, oacc[dt]);
      }
    }
    __builtin_amdgcn_s_setprio(0);
    if (more) {
      char* kn = (char*)Ks[cur ^ 1];
      char* vn = (char*)Vs[cur ^ 1];
      *(uint4*)(kn + ph0) = kr0;
      *(uint4*)(vn + ph0) = vr0;
    }
  }
#pragma unroll
  for (int dt = 0; dt < 4; ++dt) {
#pragma unroll
    for (int r = 0; r < 4; ++r) {
      const int q = p * 128 + wid * 16 + (lhi << 2) + r;
      const float v = oacc[dt][r] / lrun[r];
      ao[(size_t)((bh / HH) * TT + q) * CC + (bh % HH) * HDIM + dt * 16 + l15] = f2b(v);
    }
  }
}

extern "C" void kernel_launch(void* const* d_in, const int* in_sizes, int n_in,
                              void* d_out, int out_size, void* d_ws, size_t ws_size,
                              hipStream_t stream) {
  (void)in_sizes; (void)n_in; (void)out_size;
  const int*   idx  = (const int*)d_in[0];
  const float* tok  = (const float*)d_in[1];
  const float* pos  = (const float*)d_in[2];
  const float* Wqkv = (const float*)d_in[3];
  const float* Wpro = (const float*)d_in[4];
  const float* W1   = (const float*)d_in[5];
  const float* b1   = (const float*)d_in[6];
  const float* W2   = (const float*)d_in[7];
  const float* b2   = (const float*)d_in[8];
  const float* g1   = (const float*)d_in[9];
  const float* be1  = (const float*)d_in[10];
  const float* g2   = (const float*)d_in[11];
  const float* be2  = (const float*)d_in[12];
  const float* gf   = (const float*)d_in[13];
  const float* bfb  = (const float*)d_in[14];
  float* out = (float*)d_out;

  const size_t QS = (size_t)CC * 3 * CC;
  const size_t PS = (size_t)CC * CC;
  const size_t S1 = (size_t)CC * DFF;
  const size_t S2 = (size_t)DFF * CC;

  char* p = (char*)d_ws;
  uint16_t* x = (uint16_t*)p;      p += (size_t)MM * CC * 2;
  uint16_t* act = (uint16_t*)p;    p += (size_t)MM * CC * 2;
  uint16_t* big = (uint16_t*)p;    p += (size_t)MM * DFF * 2;
  uint16_t* tokb = (uint16_t*)p;   p += (size_t)VV * CC * 2;
  uint16_t* partb = (uint16_t*)p;  p += (size_t)2 * MM * CC * 2;
  char* pbase = p;
  uint16_t* wqA = (uint16_t*)p;    p += QS * LNUM * 2;
  uint16_t* wpA = (uint16_t*)p;    p += PS * LNUM * 2;
  uint16_t* w1A = (uint16_t*)p;    p += S1 * LNUM * 2;
  uint16_t* w2A = (uint16_t*)p;    p += S2 * LNUM * 2;
  const bool roomy2 = ws_size >= (size_t)(p - (char*)d_ws);
  if (!roomy2) {
    p = pbase;
    wqA = (uint16_t*)p; p += QS * 2;
    wpA = (uint16_t*)p; p += PS * 2;
    w1A = (uint16_t*)p; p += S1 * 2;
    w2A = (uint16_t*)p; p += S2 * 2;
  }

  cvt4_k<<<dim3((VV * CC / 4 + 255) / 256), 256, 0, stream>>>(tok, tokb, VV * CC / 4);
  embed_k<<<dim3(MM * (CC / 4) / 256), 256, 0, stream>>>(idx, tok, pos, x);
  ln_k<<<dim3(MM / 4), 256, 0, stream>>>(x, g1, be1, act);
  if (roomy2)
    tca_k<<<dim3(LNUM * 3456), 256, 0, stream>>>(Wqkv, Wpro, W1, W2, wqA, wpA, w1A, w2A);

  for (int l = 0; l < LNUM; ++l) {
    if (!roomy2)
      tca_k<<<dim3(3456), 256, 0, stream>>>(Wqkv + (size_t)l * QS, Wpro + (size_t)l * PS,
                                            W1 + (size_t)l * S1, W2 + (size_t)l * S2,
                                            wqA, wpA, w1A, w2A);
    const size_t lw = roomy2 ? (size_t)l : 0;
    gemm_k<5><<<dim3(MM / 128, 3 * CC / 128, 1), 256, 0, stream>>>(
        act, wqA + lw * QS, 3 * CC, CC, nullptr, big, nullptr);
    attn_k<<<dim3((TT / 128) * BB * HH), 512, 0, stream>>>(big, act);
    gemm_k<8><<<dim3(MM / 128, CC / 128, 2), 256, 0, stream>>>(
        act, wpA + lw * PS, CC, CC, nullptr, partb, nullptr);
    lnrb_k<2><<<dim3(MM / 4), 256, 0, stream>>>(x, partb,
                                                g2 + (size_t)l * CC, be2 + (size_t)l * CC, act);
    gemm_k<2><<<dim3(MM / 128, DFF / 128, 1), 256, 0, stream>>>(
        act, w1A + lw * S1, DFF, CC, b1 + (size_t)l * DFF, big, nullptr);
    const float* ng = (l + 1 < LNUM) ? g1 + (size_t)(l + 1) * CC : gf;
    const float* nb = (l + 1 < LNUM) ? be1 + (size_t)(l + 1) * CC : bfb;
    gemm_k<8><<<dim3(MM / 128, CC / 128, 2), 256, 0, stream>>>(
        big, w2A + lw * S2, CC, DFF, b2 + (size_t)l * CC, partb, nullptr);
    lnrb_k<2><<<dim3(MM / 4), 256, 0, stream>>>(x, partb, ng, nb, act);
  }
  gemm_k<1><<<dim3(MM / 128, VV / 128, 1), 256, 0, stream>>>(
      act, tokb, VV, CC, nullptr, nullptr, out);
}

// Round 16
// 1502.195 us; speedup vs baseline: 1.1260x; 1.1260x over previous
//
#include <hip/hip_runtime.h>
#include <hip/hip_bf16.h>
#include <stdint.h>

#define LNUM 6
#define BB 8
#define TT 1024
#define CC 768
#define HH 12
#define HDIM 64
#define DFF 3072
#define VV 512
#define MM (BB*TT)
#define QKREG ((size_t)BB*HH*TT*64)

typedef __bf16 bf16x8 __attribute__((ext_vector_type(8)));
typedef float f32x4 __attribute__((ext_vector_type(4)));

__device__ __forceinline__ uint16_t f2b(float f) {
  uint32_t u = __float_as_uint(f);
  u += 0x7FFFu + ((u >> 16) & 1u);
  return (uint16_t)(u >> 16);
}

__device__ __forceinline__ float b2f(uint16_t u) {
  return __uint_as_float((uint32_t)u << 16);
}

__device__ __forceinline__ void gld16(const uint16_t* g, uint16_t* l) {
  __builtin_amdgcn_global_load_lds(
      (const __attribute__((address_space(1))) uint32_t*)g,
      (__attribute__((address_space(3))) uint32_t*)l, 16, 0, 0);
}

__device__ __forceinline__ f32x4 mfma16(bf16x8 a, bf16x8 b, f32x4 c) {
  return __builtin_amdgcn_mfma_f32_16x16x32_bf16(a, b, c, 0, 0, 0);
}

// ---------------- convert f32 -> bf16 ----------------
__global__ __launch_bounds__(256) void cvt4_k(const float* __restrict__ in,
                                              uint16_t* __restrict__ out, int n4) {
  const int gid = blockIdx.x * 256 + threadIdx.x;
  if (gid >= n4) return;
  const float4 v = ((const float4*)in)[gid];
  ushort4 w; w.x = f2b(v.x); w.y = f2b(v.y); w.z = f2b(v.z); w.w = f2b(v.w);
  ((ushort4*)out)[gid] = w;
}

// ---------------- embedding: x(bf16) = tok_emb[idx] + pos_emb ----------------
__global__ __launch_bounds__(256) void embed_k(const int* __restrict__ idx,
                                               const float* __restrict__ tok,
                                               const float* __restrict__ pos,
                                               uint16_t* __restrict__ x) {
  const int gid = blockIdx.x * 256 + threadIdx.x;
  const int row = gid / (CC / 4), c4 = gid % (CC / 4);
  const int t = row & (TT - 1);
  const int tkn = idx[row];
  const float4 a = ((const float4*)(tok + (size_t)tkn * CC))[c4];
  const float4 q = ((const float4*)(pos + (size_t)t * CC))[c4];
  ushort4 w;
  w.x = f2b(a.x + q.x); w.y = f2b(a.y + q.y);
  w.z = f2b(a.z + q.z); w.w = f2b(a.w + q.w);
  ((ushort4*)(x + (size_t)row * CC))[c4] = w;
}

// ---------------- layernorm: bf16 x in -> bf16 out ----------------
__global__ __launch_bounds__(256) void ln_k(const uint16_t* __restrict__ x,
                                            const float* __restrict__ gamma,
                                            const float* __restrict__ beta,
                                            uint16_t* __restrict__ o) {
  const int lane = threadIdx.x & 63, wid = threadIdx.x >> 6;
  const int row = blockIdx.x * 4 + wid;
  const ushort4* xr = (const ushort4*)(x + (size_t)row * CC);
  float4 v[3]; float s = 0.f, sq = 0.f;
#pragma unroll
  for (int i = 0; i < 3; ++i) {
    const ushort4 u = xr[lane + i * 64];
    v[i] = make_float4(b2f(u.x), b2f(u.y), b2f(u.z), b2f(u.w));
    s += v[i].x + v[i].y + v[i].z + v[i].w;
    sq += v[i].x * v[i].x + v[i].y * v[i].y + v[i].z * v[i].z + v[i].w * v[i].w;
  }
#pragma unroll
  for (int m = 1; m < 64; m <<= 1) { s += __shfl_xor(s, m, 64); sq += __shfl_xor(sq, m, 64); }
  const float mu = s * (1.f / 768.f);
  const float rstd = rsqrtf(sq * (1.f / 768.f) - mu * mu + 1e-5f);
  ushort4* orow = (ushort4*)(o + (size_t)row * CC);
#pragma unroll
  for (int i = 0; i < 3; ++i) {
    const int c4 = lane + i * 64;
    const float4 gg = ((const float4*)gamma)[c4];
    const float4 bb = ((const float4*)beta)[c4];
    ushort4 w;
    w.x = f2b((v[i].x - mu) * rstd * gg.x + bb.x);
    w.y = f2b((v[i].y - mu) * rstd * gg.y + bb.y);
    w.z = f2b((v[i].z - mu) * rstd * gg.z + bb.z);
    w.w = f2b((v[i].w - mu) * rstd * gg.w + bb.w);
    orow[c4] = w;
  }
}

// --- layernorm + NP bf16-partial reduce: x(bf16) += sum(p_j); o = LN(x) ---
template <int NP>
__global__ __launch_bounds__(256) void lnrb_k(uint16_t* __restrict__ x,
                                              const uint16_t* __restrict__ pp,
                                              const float* __restrict__ gamma,
                                              const float* __restrict__ beta,
                                              uint16_t* __restrict__ o) {
  const int lane = threadIdx.x & 63, wid = threadIdx.x >> 6;
  const int row = blockIdx.x * 4 + wid;
  ushort4* xr = (ushort4*)(x + (size_t)row * CC);
  float4 v[3]; float s = 0.f, sq = 0.f;
#pragma unroll
  for (int i = 0; i < 3; ++i) {
    const int c4 = lane + i * 64;
    const ushort4 u = xr[c4];
    float4 a = make_float4(b2f(u.x), b2f(u.y), b2f(u.z), b2f(u.w));
#pragma unroll
    for (int j = 0; j < NP; ++j) {
      const ushort4 q =
          ((const ushort4*)(pp + (size_t)j * MM * CC + (size_t)row * CC))[c4];
      a.x += b2f(q.x); a.y += b2f(q.y); a.z += b2f(q.z); a.w += b2f(q.w);
    }
    ushort4 w;
    w.x = f2b(a.x); w.y = f2b(a.y); w.z = f2b(a.z); w.w = f2b(a.w);
    xr[c4] = w;
    v[i] = a;
    s += a.x + a.y + a.z + a.w;
    sq += a.x * a.x + a.y * a.y + a.z * a.z + a.w * a.w;
  }
#pragma unroll
  for (int m = 1; m < 64; m <<= 1) { s += __shfl_xor(s, m, 64); sq += __shfl_xor(sq, m, 64); }
  const float mu = s * (1.f / 768.f);
  const float rstd = rsqrtf(sq * (1.f / 768.f) - mu * mu + 1e-5f);
  ushort4* orow = (ushort4*)(o + (size_t)row * CC);
#pragma unroll
  for (int i = 0; i < 3; ++i) {
    const int c4 = lane + i * 64;
    const float4 gg = ((const float4*)gamma)[c4];
    const float4 bb = ((const float4*)beta)[c4];
    ushort4 w;
    w.x = f2b((v[i].x - mu) * rstd * gg.x + bb.x);
    w.y = f2b((v[i].y - mu) * rstd * gg.y + bb.y);
    w.z = f2b((v[i].z - mu) * rstd * gg.z + bb.z);
    w.w = f2b((v[i].w - mu) * rstd * gg.w + bb.w);
    orow[c4] = w;
  }
}

// ------- all-weights transpose+convert v2: 64(k)x32(n) tiles, 128B writes -------
__global__ __launch_bounds__(256) void tca_k(const float* __restrict__ Wq,
                                             const float* __restrict__ Wp,
                                             const float* __restrict__ W1p,
                                             const float* __restrict__ W2p,
                                             uint16_t* __restrict__ dq,
                                             uint16_t* __restrict__ dp,
                                             uint16_t* __restrict__ d1,
                                             uint16_t* __restrict__ d2) {
  __shared__ float tile[64][33];
  const int b = blockIdx.x;
  const int l = b / 3456;
  int r = b - l * 3456;
  const float* src; uint16_t* dst; int K, N, kt, nt;
  if (r < 864) {
    K = CC; N = 3 * CC;
    src = Wq + (size_t)l * CC * 3 * CC; dst = dq + (size_t)l * CC * 3 * CC;
    kt = r / 72; nt = r % 72;
  } else if (r < 1152) {
    r -= 864; K = CC; N = CC;
    src = Wp + (size_t)l * CC * CC; dst = dp + (size_t)l * CC * CC;
    kt = r / 24; nt = r % 24;
  } else if (r < 2304) {
    r -= 1152; K = CC; N = DFF;
    src = W1p + (size_t)l * CC * DFF; dst = d1 + (size_t)l * CC * DFF;
    kt = r / 96; nt = r % 96;
  } else {
    r -= 2304; K = DFF; N = CC;
    src = W2p + (size_t)l * DFF * CC; dst = d2 + (size_t)l * DFF * CC;
    kt = r / 24; nt = r % 24;
  }
  const int kb = kt * 64, nb = nt * 32;
  const int tx = threadIdx.x & 31, ty = threadIdx.x >> 5;
#pragma unroll
  for (int i = 0; i < 64; i += 8)
    tile[ty + i][tx] = src[(size_t)(kb + ty + i) * N + nb + tx];
  __syncthreads();
#pragma unroll
  for (int i = 0; i < 32; i += 8) {
    const int n = ty + i;
    const int k2 = tx * 2;
    const uint32_t w = (uint32_t)f2b(tile[k2][n]) | ((uint32_t)f2b(tile[k2 + 1][n]) << 16);
    *(uint32_t*)(dst + (size_t)(nb + n) * K + kb + k2) = w;
  }
}

// ---------------- 128x128 GEMM, BK=64, chunk-swizzled LDS (m97 structure) ----------------
// EPI: 1 = f32 store; 2 = bias+GELU -> bf16; 5 = qkv split; 8 = bf16 partials (+bias kp0)
template <int EPI>
__global__ __launch_bounds__(256) void gemm_k(const uint16_t* __restrict__ A,
                                              const uint16_t* __restrict__ Bt,
                                              int N, int K,
                                              const float* __restrict__ bias,
                                              uint16_t* __restrict__ outb,
                                              float* __restrict__ outf) {
  __shared__ __align__(16) uint16_t As[128 * 64];
  __shared__ __align__(16) uint16_t Bs[128 * 64];
  const int tid = threadIdx.x;
  const int lane = tid & 63, wid = tid >> 6;
  const int wm = wid >> 1, wn = wid & 1;
  const int bm = blockIdx.x * 128, bn = blockIdx.y * 128;
  const int kp = blockIdx.z;
  const int Ksub = K / (int)gridDim.z;
  const int k0b = kp * Ksub;
  const int nkt = Ksub >> 6;
  const int srow = tid >> 3;
  const int swz = (tid & 7) ^ (srow & 7);
  const uint16_t* gA0 = A + (size_t)(bm + srow) * K + k0b + swz * 8;
  const uint16_t* gB0 = Bt + (size_t)(bn + srow) * K + k0b + swz * 8;
  const size_t qs = (size_t)32 * K;
  const int l15 = lane & 15, lhi = lane >> 4;
  int aof[2][4], bof[2][4];
#pragma unroll
  for (int kk = 0; kk < 2; ++kk)
#pragma unroll
    for (int i = 0; i < 4; ++i) {
      const int sw = ((kk * 4 + lhi) ^ (l15 & 7)) * 16;
      aof[kk][i] = (wm * 64 + i * 16 + l15) * 128 + sw;
      bof[kk][i] = (wn * 64 + i * 16 + l15) * 128 + sw;
    }
  f32x4 acc[4][4] = {};
  for (int t = 0; t < nkt; ++t) {
    const int ko = t * 64;
#pragma unroll
    for (int q = 0; q < 4; ++q) {
      gld16(gA0 + q * qs + ko, &As[q * 2048 + tid * 8]);
      gld16(gB0 + q * qs + ko, &Bs[q * 2048 + tid * 8]);
    }
    __syncthreads();
    const char* Ab = (const char*)As;
    const char* Bb = (const char*)Bs;
#pragma unroll
    for (int kk = 0; kk < 2; ++kk) {
      bf16x8 a[4], b[4];
#pragma unroll
      for (int i = 0; i < 4; ++i) {
        a[i] = *(const bf16x8*)(Ab + aof[kk][i]);
        b[i] = *(const bf16x8*)(Bb + bof[kk][i]);
      }
#pragma unroll
      for (int i = 0; i < 4; ++i)
#pragma unroll
        for (int j = 0; j < 4; ++j)
          acc[i][j] = mfma16(a[i], b[j], acc[i][j]);
    }
    __syncthreads();
  }
#pragma unroll
  for (int i = 0; i < 4; ++i) {
    const int m0 = bm + wm * 64 + i * 16 + (lhi << 2);
#pragma unroll
    for (int j = 0; j < 4; ++j) {
      const int n = bn + wn * 64 + j * 16 + l15;
      if constexpr (EPI == 5) {
        const int sec = n / CC;
        const int rn = n - sec * CC;
        const int hh = rn >> 6, d = rn & 63;
        const int b = m0 >> 10, t0 = m0 & 1023;
        if (sec == 2) {
          ushort4 w;
          w.x = f2b(acc[i][j][0]); w.y = f2b(acc[i][j][1]);
          w.z = f2b(acc[i][j][2]); w.w = f2b(acc[i][j][3]);
          *(ushort4*)(outb + 2 * QKREG + ((size_t)(b * HH + hh) * 64 + d) * TT + t0) = w;
        } else {
          uint16_t* dst = outb + (size_t)sec * QKREG + ((size_t)(b * HH + hh) * TT + t0) * 64 + d;
#pragma unroll
          for (int rr = 0; rr < 4; ++rr) dst[(size_t)rr * 64] = f2b(acc[i][j][rr]);
        }
      } else if constexpr (EPI == 8) {
        uint16_t* pdst = outb + (size_t)kp * ((size_t)MM * N);
        const float bb = (kp == 0 && bias) ? bias[n] : 0.f;
#pragma unroll
        for (int rr = 0; rr < 4; ++rr)
          pdst[(size_t)(m0 + rr) * N + n] = f2b(acc[i][j][rr] + bb);
      } else {
#pragma unroll
        for (int rr = 0; rr < 4; ++rr) {
          const size_t o = (size_t)(m0 + rr) * N + n;
          const float v = acc[i][j][rr];
          if constexpr (EPI == 1) {
            outf[o] = v;
          } else if constexpr (EPI == 2) {
            float t = v + bias[n];
            t = 0.5f * t * (1.0f + erff(t * 0.70710678118654752f));
            outb[o] = f2b(t);
          }
        }
      }
    }
  }
}

// ---- fused causal flash attention: QBLK=128 (8 waves), dbuf K/V, 1 barrier/tile ----
__global__ __launch_bounds__(512) void attn_k(const uint16_t* __restrict__ qkvh,
                                              uint16_t* __restrict__ ao) {
  __shared__ __align__(16) uint16_t Ks[2][64 * 64], Vs[2][64 * 64];
  __shared__ __align__(16) uint16_t Ps[8][16 * 64];
  const int tid = threadIdx.x, lane = tid & 63, wid = tid >> 6;
  const int p = (TT / 128 - 1) - blockIdx.x / (BB * HH);
  const int bh = blockIdx.x % (BB * HH);
  const uint16_t* qb = qkvh + (size_t)bh * (TT * 64);
  const uint16_t* kb = qkvh + QKREG + (size_t)bh * (TT * 64);
  const uint16_t* vb = qkvh + 2 * QKREG + (size_t)bh * ((size_t)64 * TT);
  const int l15 = lane & 15, lhi = lane >> 4;
  bf16x8 qf[2];
  {
    const uint16_t* qr = qb + (size_t)(p * 128 + wid * 16 + l15) * 64 + lhi * 8;
    qf[0] = *(const bf16x8*)qr;
    qf[1] = *(const bf16x8*)(qr + 32);
  }
  const int r0 = tid >> 3;
  const int cb0 = (tid & 7) * 16;
  const int ph0 = r0 * 128 + (cb0 ^ ((r0 & 7) << 4));

  uint4 kr0, vr0;
  kr0 = *(const uint4*)(kb + (size_t)r0 * 64 + cb0 / 2);
  vr0 = *(const uint4*)(vb + (size_t)r0 * TT + cb0 / 2);
  *(uint4*)((char*)Ks[0] + ph0) = kr0;
  *(uint4*)((char*)Vs[0] + ph0) = vr0;

  f32x4 oacc[4] = {};
  float mrun[4] = {-INFINITY, -INFINITY, -INFINITY, -INFINITY};
  float lrun[4] = {0.f, 0.f, 0.f, 0.f};
  char* pb = (char*)Ps[wid];
  const int jmax = 2 * p + 1;
  const int qgmin = p * 128 + wid * 16;

  for (int j = 0; j <= jmax; ++j) {
    const int cur = j & 1;
    const bool more = (j < jmax);
    __syncthreads();
    if (more) {
      const int jn = (j + 1) * 64;
      kr0 = *(const uint4*)(kb + (size_t)(jn + r0) * 64 + cb0 / 2);
      vr0 = *(const uint4*)(vb + (size_t)r0 * TT + jn + cb0 / 2);
    }
    const char* Kb = (const char*)Ks[cur];
    const char* Vb = (const char*)Vs[cur];
    f32x4 s4[4] = {};
    __builtin_amdgcn_s_setprio(1);
#pragma unroll
    for (int kk = 0; kk < 2; ++kk) {
      const int cbyte = kk * 64 + lhi * 16;
#pragma unroll
      for (int nt = 0; nt < 4; ++nt) {
        const int krow = nt * 16 + l15;
        const bf16x8 kf = *(const bf16x8*)(Kb + krow * 128 + (cbyte ^ ((krow & 7) << 4)));
        s4[nt] = mfma16(qf[kk], kf, s4[nt]);
      }
    }
    __builtin_amdgcn_s_setprio(0);
    const bool diag = (j * 64 + 63) > qgmin;
    float alpha[4];
#pragma unroll
    for (int r = 0; r < 4; ++r) {
      const int qg = qgmin + (lhi << 2) + r;
      float mx = -INFINITY;
#pragma unroll
      for (int nt = 0; nt < 4; ++nt) {
        float v = s4[nt][r] * 0.125f;
        if (diag && (j * 64 + nt * 16 + l15) > qg) v = -INFINITY;
        s4[nt][r] = v;
        mx = fmaxf(mx, v);
      }
#pragma unroll
      for (int m = 1; m < 16; m <<= 1) mx = fmaxf(mx, __shfl_xor(mx, m, 16));
      const float mnew = fmaxf(mrun[r], mx);
      alpha[r] = __expf(mrun[r] - mnew);
      float ps = 0.f;
#pragma unroll
      for (int nt = 0; nt < 4; ++nt) {
        const float pp = __expf(s4[nt][r] - mnew);
        s4[nt][r] = pp;
        ps += pp;
      }
#pragma unroll
      for (int m = 1; m < 16; m <<= 1) ps += __shfl_xor(ps, m, 16);
      lrun[r] = lrun[r] * alpha[r] + ps;
      mrun[r] = mnew;
    }
#pragma unroll
    for (int dt = 0; dt < 4; ++dt)
#pragma unroll
      for (int r = 0; r < 4; ++r) oacc[dt][r] *= alpha[r];
#pragma unroll
    for (int r = 0; r < 4; ++r) {
      const int prow = (lhi << 2) + r;
      const int swp = (prow & 7) << 4;
#pragma unroll
      for (int nt = 0; nt < 4; ++nt) {
        const int cb = (nt * 16 + l15) * 2;
        *(uint16_t*)(pb + prow * 128 + (cb ^ swp)) = f2b(s4[nt][r]);
      }
    }
    __builtin_amdgcn_s_setprio(1);
#pragma unroll
    for (int kk = 0; kk < 2; ++kk) {
      const int cbyte = kk * 64 + lhi * 16;
      const bf16x8 pf = *(const bf16x8*)(pb + l15 * 128 + (cbyte ^ ((l15 & 7) << 4)));
#pragma unroll
      for (int dt = 0; dt < 4; ++dt) {
        const int vrow = dt * 16 + l15;
        const bf16x8 vf = *(const bf16x8*)(Vb + vrow * 128 + (cbyte ^ ((vrow & 7) << 4)));
        oacc[dt] = mfma16(pf, vf, oacc[dt]);
      }
    }
    __builtin_amdgcn_s_setprio(0);
    if (more) {
      char* kn = (char*)Ks[cur ^ 1];
      char* vn = (char*)Vs[cur ^ 1];
      *(uint4*)(kn + ph0) = kr0;
      *(uint4*)(vn + ph0) = vr0;
    }
  }
#pragma unroll
  for (int dt = 0; dt < 4; ++dt) {
#pragma unroll
    for (int r = 0; r < 4; ++r) {
      const int q = p * 128 + wid * 16 + (lhi << 2) + r;
      const float v = oacc[dt][r] / lrun[r];
      ao[(size_t)((bh / HH) * TT + q) * CC + (bh % HH) * HDIM + dt * 16 + l15] = f2b(v);
    }
  }
}

extern "C" void kernel_launch(void* const* d_in, const int* in_sizes, int n_in,
                              void* d_out, int out_size, void* d_ws, size_t ws_size,
                              hipStream_t stream) {
  (void)in_sizes; (void)n_in; (void)out_size;
  const int*   idx  = (const int*)d_in[0];
  const float* tok  = (const float*)d_in[1];
  const float* pos  = (const float*)d_in[2];
  const float* Wqkv = (const float*)d_in[3];
  const float* Wpro = (const float*)d_in[4];
  const float* W1   = (const float*)d_in[5];
  const float* b1   = (const float*)d_in[6];
  const float* W2   = (const float*)d_in[7];
  const float* b2   = (const float*)d_in[8];
  const float* g1   = (const float*)d_in[9];
  const float* be1  = (const float*)d_in[10];
  const float* g2   = (const float*)d_in[11];
  const float* be2  = (const float*)d_in[12];
  const float* gf   = (const float*)d_in[13];
  const float* bfb  = (const float*)d_in[14];
  float* out = (float*)d_out;

  const size_t QS = (size_t)CC * 3 * CC;
  const size_t PS = (size_t)CC * CC;
  const size_t S1 = (size_t)CC * DFF;
  const size_t S2 = (size_t)DFF * CC;

  char* p = (char*)d_ws;
  uint16_t* x = (uint16_t*)p;      p += (size_t)MM * CC * 2;
  uint16_t* act = (uint16_t*)p;    p += (size_t)MM * CC * 2;
  uint16_t* big = (uint16_t*)p;    p += (size_t)MM * DFF * 2;
  uint16_t* tokb = (uint16_t*)p;   p += (size_t)VV * CC * 2;
  uint16_t* partb = (uint16_t*)p;  p += (size_t)2 * MM * CC * 2;
  char* pbase = p;
  uint16_t* wqA = (uint16_t*)p;    p += QS * LNUM * 2;
  uint16_t* wpA = (uint16_t*)p;    p += PS * LNUM * 2;
  uint16_t* w1A = (uint16_t*)p;    p += S1 * LNUM * 2;
  uint16_t* w2A = (uint16_t*)p;    p += S2 * LNUM * 2;
  const bool roomy2 = ws_size >= (size_t)(p - (char*)d_ws);
  if (!roomy2) {
    p = pbase;
    wqA = (uint16_t*)p; p += QS * 2;
    wpA = (uint16_t*)p; p += PS * 2;
    w1A = (uint16_t*)p; p += S1 * 2;
    w2A = (uint16_t*)p; p += S2 * 2;
  }

  cvt4_k<<<dim3((VV * CC / 4 + 255) / 256), 256, 0, stream>>>(tok, tokb, VV * CC / 4);
  embed_k<<<dim3(MM * (CC / 4) / 256), 256, 0, stream>>>(idx, tok, pos, x);
  ln_k<<<dim3(MM / 4), 256, 0, stream>>>(x, g1, be1, act);
  if (roomy2)
    tca_k<<<dim3(LNUM * 3456), 256, 0, stream>>>(Wqkv, Wpro, W1, W2, wqA, wpA, w1A, w2A);

  for (int l = 0; l < LNUM; ++l) {
    if (!roomy2)
      tca_k<<<dim3(3456), 256, 0, stream>>>(Wqkv + (size_t)l * QS, Wpro + (size_t)l * PS,
                                            W1 + (size_t)l * S1, W2 + (size_t)l * S2,
                                            wqA, wpA, w1A, w2A);
    const size_t lw = roomy2 ? (size_t)l : 0;
    gemm_k<5><<<dim3(MM / 128, 3 * CC / 128, 1), 256, 0, stream>>>(
        act, wqA + lw * QS, 3 * CC, CC, nullptr, big, nullptr);
    attn_k<<<dim3((TT / 128) * BB * HH), 512, 0, stream>>>(big, act);
    gemm_k<8><<<dim3(MM / 128, CC / 128, 2), 256, 0, stream>>>(
        act, wpA + lw * PS, CC, CC, nullptr, partb, nullptr);
    lnrb_k<2><<<dim3(MM / 4), 256, 0, stream>>>(x, partb,
                                                g2 + (size_t)l * CC, be2 + (size_t)l * CC, act);
    gemm_k<2><<<dim3(MM / 128, DFF / 128, 1), 256, 0, stream>>>(
        act, w1A + lw * S1, DFF, CC, b1 + (size_t)l * DFF, big, nullptr);
    const float* ng = (l + 1 < LNUM) ? g1 + (size_t)(l + 1) * CC : gf;
    const float* nb = (l + 1 < LNUM) ? be1 + (size_t)(l + 1) * CC : bfb;
    gemm_k<8><<<dim3(MM / 128, CC / 128, 2), 256, 0, stream>>>(
        big, w2A + lw * S2, CC, DFF, b2 + (size_t)l * CC, partb, nullptr);
    lnrb_k<2><<<dim3(MM / 4), 256, 0, stream>>>(x, partb, ng, nb, act);
  }
  gemm_k<1><<<dim3(MM / 128, VV / 128, 1), 256, 0, stream>>>(
      act, tokb, VV, CC, nullptr, nullptr, out);
}

// Round 17
// 1477.628 us; speedup vs baseline: 1.1447x; 1.0166x over previous
//
#include <hip/hip_runtime.h>
#include <hip/hip_bf16.h>
#include <stdint.h>

#define LNUM 6
#define BB 8
#define TT 1024
#define CC 768
#define HH 12
#define HDIM 64
#define DFF 3072
#define VV 512
#define MM (BB*TT)
#define QKREG ((size_t)BB*HH*TT*64)

typedef __bf16 bf16x8 __attribute__((ext_vector_type(8)));
typedef float f32x4 __attribute__((ext_vector_type(4)));

__device__ __forceinline__ uint16_t f2b(float f) {
  uint32_t u = __float_as_uint(f);
  u += 0x7FFFu + ((u >> 16) & 1u);
  return (uint16_t)(u >> 16);
}

__device__ __forceinline__ float b2f(uint16_t u) {
  return __uint_as_float((uint32_t)u << 16);
}

__device__ __forceinline__ void gld16(const uint16_t* g, uint16_t* l) {
  __builtin_amdgcn_global_load_lds(
      (const __attribute__((address_space(1))) uint32_t*)g,
      (__attribute__((address_space(3))) uint32_t*)l, 16, 0, 0);
}

__device__ __forceinline__ f32x4 mfma16(bf16x8 a, bf16x8 b, f32x4 c) {
  return __builtin_amdgcn_mfma_f32_16x16x32_bf16(a, b, c, 0, 0, 0);
}

// ---------------- convert f32 -> bf16 ----------------
__global__ __launch_bounds__(256) void cvt4_k(const float* __restrict__ in,
                                              uint16_t* __restrict__ out, int n4) {
  const int gid = blockIdx.x * 256 + threadIdx.x;
  if (gid >= n4) return;
  const float4 v = ((const float4*)in)[gid];
  ushort4 w; w.x = f2b(v.x); w.y = f2b(v.y); w.z = f2b(v.z); w.w = f2b(v.w);
  ((ushort4*)out)[gid] = w;
}

// ---------------- embedding: x(bf16) = tok_emb[idx] + pos_emb ----------------
__global__ __launch_bounds__(256) void embed_k(const int* __restrict__ idx,
                                               const float* __restrict__ tok,
                                               const float* __restrict__ pos,
                                               uint16_t* __restrict__ x) {
  const int gid = blockIdx.x * 256 + threadIdx.x;
  const int row = gid / (CC / 4), c4 = gid % (CC / 4);
  const int t = row & (TT - 1);
  const int tkn = idx[row];
  const float4 a = ((const float4*)(tok + (size_t)tkn * CC))[c4];
  const float4 q = ((const float4*)(pos + (size_t)t * CC))[c4];
  ushort4 w;
  w.x = f2b(a.x + q.x); w.y = f2b(a.y + q.y);
  w.z = f2b(a.z + q.z); w.w = f2b(a.w + q.w);
  ((ushort4*)(x + (size_t)row * CC))[c4] = w;
}

// ---------------- layernorm: bf16 x in -> bf16 out ----------------
__global__ __launch_bounds__(256) void ln_k(const uint16_t* __restrict__ x,
                                            const float* __restrict__ gamma,
                                            const float* __restrict__ beta,
                                            uint16_t* __restrict__ o) {
  const int lane = threadIdx.x & 63, wid = threadIdx.x >> 6;
  const int row = blockIdx.x * 4 + wid;
  const ushort4* xr = (const ushort4*)(x + (size_t)row * CC);
  float4 v[3]; float s = 0.f, sq = 0.f;
#pragma unroll
  for (int i = 0; i < 3; ++i) {
    const ushort4 u = xr[lane + i * 64];
    v[i] = make_float4(b2f(u.x), b2f(u.y), b2f(u.z), b2f(u.w));
    s += v[i].x + v[i].y + v[i].z + v[i].w;
    sq += v[i].x * v[i].x + v[i].y * v[i].y + v[i].z * v[i].z + v[i].w * v[i].w;
  }
#pragma unroll
  for (int m = 1; m < 64; m <<= 1) { s += __shfl_xor(s, m, 64); sq += __shfl_xor(sq, m, 64); }
  const float mu = s * (1.f / 768.f);
  const float rstd = rsqrtf(sq * (1.f / 768.f) - mu * mu + 1e-5f);
  ushort4* orow = (ushort4*)(o + (size_t)row * CC);
#pragma unroll
  for (int i = 0; i < 3; ++i) {
    const int c4 = lane + i * 64;
    const float4 gg = ((const float4*)gamma)[c4];
    const float4 bb = ((const float4*)beta)[c4];
    ushort4 w;
    w.x = f2b((v[i].x - mu) * rstd * gg.x + bb.x);
    w.y = f2b((v[i].y - mu) * rstd * gg.y + bb.y);
    w.z = f2b((v[i].z - mu) * rstd * gg.z + bb.z);
    w.w = f2b((v[i].w - mu) * rstd * gg.w + bb.w);
    orow[c4] = w;
  }
}

// --- layernorm + NP bf16-partial reduce: x(bf16) += sum(p_j); o = LN(x) ---
// WX=false skips the x writeback (final layer: x is dead after lnf input).
template <int NP, bool WX>
__global__ __launch_bounds__(256) void lnrb_k(uint16_t* __restrict__ x,
                                              const uint16_t* __restrict__ pp,
                                              const float* __restrict__ gamma,
                                              const float* __restrict__ beta,
                                              uint16_t* __restrict__ o) {
  const int lane = threadIdx.x & 63, wid = threadIdx.x >> 6;
  const int row = blockIdx.x * 4 + wid;
  ushort4* xr = (ushort4*)(x + (size_t)row * CC);
  float4 v[3]; float s = 0.f, sq = 0.f;
#pragma unroll
  for (int i = 0; i < 3; ++i) {
    const int c4 = lane + i * 64;
    const ushort4 u = xr[c4];
    float4 a = make_float4(b2f(u.x), b2f(u.y), b2f(u.z), b2f(u.w));
#pragma unroll
    for (int j = 0; j < NP; ++j) {
      const ushort4 q =
          ((const ushort4*)(pp + (size_t)j * MM * CC + (size_t)row * CC))[c4];
      a.x += b2f(q.x); a.y += b2f(q.y); a.z += b2f(q.z); a.w += b2f(q.w);
    }
    if (WX) {
      ushort4 w;
      w.x = f2b(a.x); w.y = f2b(a.y); w.z = f2b(a.z); w.w = f2b(a.w);
      xr[c4] = w;
    }
    v[i] = a;
    s += a.x + a.y + a.z + a.w;
    sq += a.x * a.x + a.y * a.y + a.z * a.z + a.w * a.w;
  }
#pragma unroll
  for (int m = 1; m < 64; m <<= 1) { s += __shfl_xor(s, m, 64); sq += __shfl_xor(sq, m, 64); }
  const float mu = s * (1.f / 768.f);
  const float rstd = rsqrtf(sq * (1.f / 768.f) - mu * mu + 1e-5f);
  ushort4* orow = (ushort4*)(o + (size_t)row * CC);
#pragma unroll
  for (int i = 0; i < 3; ++i) {
    const int c4 = lane + i * 64;
    const float4 gg = ((const float4*)gamma)[c4];
    const float4 bb = ((const float4*)beta)[c4];
    ushort4 w;
    w.x = f2b((v[i].x - mu) * rstd * gg.x + bb.x);
    w.y = f2b((v[i].y - mu) * rstd * gg.y + bb.y);
    w.z = f2b((v[i].z - mu) * rstd * gg.z + bb.z);
    w.w = f2b((v[i].w - mu) * rstd * gg.w + bb.w);
    orow[c4] = w;
  }
}

// ------- all-weights transpose+convert v2: 64(k)x32(n) tiles, 128B writes -------
__global__ __launch_bounds__(256) void tca_k(const float* __restrict__ Wq,
                                             const float* __restrict__ Wp,
                                             const float* __restrict__ W1p,
                                             const float* __restrict__ W2p,
                                             uint16_t* __restrict__ dq,
                                             uint16_t* __restrict__ dp,
                                             uint16_t* __restrict__ d1,
                                             uint16_t* __restrict__ d2) {
  __shared__ float tile[64][33];
  const int b = blockIdx.x;
  const int l = b / 3456;
  int r = b - l * 3456;
  const float* src; uint16_t* dst; int K, N, kt, nt;
  if (r < 864) {
    K = CC; N = 3 * CC;
    src = Wq + (size_t)l * CC * 3 * CC; dst = dq + (size_t)l * CC * 3 * CC;
    kt = r / 72; nt = r % 72;
  } else if (r < 1152) {
    r -= 864; K = CC; N = CC;
    src = Wp + (size_t)l * CC * CC; dst = dp + (size_t)l * CC * CC;
    kt = r / 24; nt = r % 24;
  } else if (r < 2304) {
    r -= 1152; K = CC; N = DFF;
    src = W1p + (size_t)l * CC * DFF; dst = d1 + (size_t)l * CC * DFF;
    kt = r / 96; nt = r % 96;
  } else {
    r -= 2304; K = DFF; N = CC;
    src = W2p + (size_t)l * DFF * CC; dst = d2 + (size_t)l * DFF * CC;
    kt = r / 24; nt = r % 24;
  }
  const int kb = kt * 64, nb = nt * 32;
  const int tx = threadIdx.x & 31, ty = threadIdx.x >> 5;
#pragma unroll
  for (int i = 0; i < 64; i += 8)
    tile[ty + i][tx] = src[(size_t)(kb + ty + i) * N + nb + tx];
  __syncthreads();
#pragma unroll
  for (int i = 0; i < 32; i += 8) {
    const int n = ty + i;
    const int k2 = tx * 2;
    const uint32_t w = (uint32_t)f2b(tile[k2][n]) | ((uint32_t)f2b(tile[k2 + 1][n]) << 16);
    *(uint32_t*)(dst + (size_t)(nb + n) * K + kb + k2) = w;
  }
}

// ---------------- 128x128 GEMM, BK=64, chunk-swizzled LDS (m97 structure) ----------------
// EPI: 1 = f32 store; 2 = bias+GELU -> bf16; 5 = qkv split; 8 = bf16 partials (+bias kp0)
// NOTE: EPI 8 with gridDim.z==1 is a plain bf16 store (optionally +bias).
template <int EPI>
__global__ __launch_bounds__(256) void gemm_k(const uint16_t* __restrict__ A,
                                              const uint16_t* __restrict__ Bt,
                                              int N, int K,
                                              const float* __restrict__ bias,
                                              uint16_t* __restrict__ outb,
                                              float* __restrict__ outf) {
  __shared__ __align__(16) uint16_t As[128 * 64];
  __shared__ __align__(16) uint16_t Bs[128 * 64];
  const int tid = threadIdx.x;
  const int lane = tid & 63, wid = tid >> 6;
  const int wm = wid >> 1, wn = wid & 1;
  const int bm = blockIdx.x * 128, bn = blockIdx.y * 128;
  const int kp = blockIdx.z;
  const int Ksub = K / (int)gridDim.z;
  const int k0b = kp * Ksub;
  const int nkt = Ksub >> 6;
  const int srow = tid >> 3;
  const int swz = (tid & 7) ^ (srow & 7);
  const uint16_t* gA0 = A + (size_t)(bm + srow) * K + k0b + swz * 8;
  const uint16_t* gB0 = Bt + (size_t)(bn + srow) * K + k0b + swz * 8;
  const size_t qs = (size_t)32 * K;
  const int l15 = lane & 15, lhi = lane >> 4;
  int aof[2][4], bof[2][4];
#pragma unroll
  for (int kk = 0; kk < 2; ++kk)
#pragma unroll
    for (int i = 0; i < 4; ++i) {
      const int sw = ((kk * 4 + lhi) ^ (l15 & 7)) * 16;
      aof[kk][i] = (wm * 64 + i * 16 + l15) * 128 + sw;
      bof[kk][i] = (wn * 64 + i * 16 + l15) * 128 + sw;
    }
  f32x4 acc[4][4] = {};
  for (int t = 0; t < nkt; ++t) {
    const int ko = t * 64;
#pragma unroll
    for (int q = 0; q < 4; ++q) {
      gld16(gA0 + q * qs + ko, &As[q * 2048 + tid * 8]);
      gld16(gB0 + q * qs + ko, &Bs[q * 2048 + tid * 8]);
    }
    __syncthreads();
    const char* Ab = (const char*)As;
    const char* Bb = (const char*)Bs;
#pragma unroll
    for (int kk = 0; kk < 2; ++kk) {
      bf16x8 a[4], b[4];
#pragma unroll
      for (int i = 0; i < 4; ++i) {
        a[i] = *(const bf16x8*)(Ab + aof[kk][i]);
        b[i] = *(const bf16x8*)(Bb + bof[kk][i]);
      }
#pragma unroll
      for (int i = 0; i < 4; ++i)
#pragma unroll
        for (int j = 0; j < 4; ++j)
          acc[i][j] = mfma16(a[i], b[j], acc[i][j]);
    }
    __syncthreads();
  }
#pragma unroll
  for (int i = 0; i < 4; ++i) {
    const int m0 = bm + wm * 64 + i * 16 + (lhi << 2);
#pragma unroll
    for (int j = 0; j < 4; ++j) {
      const int n = bn + wn * 64 + j * 16 + l15;
      if constexpr (EPI == 5) {
        const int sec = n / CC;
        const int rn = n - sec * CC;
        const int hh = rn >> 6, d = rn & 63;
        const int b = m0 >> 10, t0 = m0 & 1023;
        if (sec == 2) {
          ushort4 w;
          w.x = f2b(acc[i][j][0]); w.y = f2b(acc[i][j][1]);
          w.z = f2b(acc[i][j][2]); w.w = f2b(acc[i][j][3]);
          *(ushort4*)(outb + 2 * QKREG + ((size_t)(b * HH + hh) * 64 + d) * TT + t0) = w;
        } else {
          uint16_t* dst = outb + (size_t)sec * QKREG + ((size_t)(b * HH + hh) * TT + t0) * 64 + d;
#pragma unroll
          for (int rr = 0; rr < 4; ++rr) dst[(size_t)rr * 64] = f2b(acc[i][j][rr]);
        }
      } else if constexpr (EPI == 8) {
        uint16_t* pdst = outb + (size_t)kp * ((size_t)MM * N);
        const float bb = (kp == 0 && bias) ? bias[n] : 0.f;
#pragma unroll
        for (int rr = 0; rr < 4; ++rr)
          pdst[(size_t)(m0 + rr) * N + n] = f2b(acc[i][j][rr] + bb);
      } else {
#pragma unroll
        for (int rr = 0; rr < 4; ++rr) {
          const size_t o = (size_t)(m0 + rr) * N + n;
          const float v = acc[i][j][rr];
          if constexpr (EPI == 1) {
            outf[o] = v;
          } else if constexpr (EPI == 2) {
            float t = v + bias[n];
            t = 0.5f * t * (1.0f + erff(t * 0.70710678118654752f));
            outb[o] = f2b(t);
          }
        }
      }
    }
  }
}

// ---- fused causal flash attention: QBLK=128 (8 waves), dbuf K/V, 1 barrier/tile ----
__global__ __launch_bounds__(512) void attn_k(const uint16_t* __restrict__ qkvh,
                                              uint16_t* __restrict__ ao) {
  __shared__ __align__(16) uint16_t Ks[2][64 * 64], Vs[2][64 * 64];
  __shared__ __align__(16) uint16_t Ps[8][16 * 64];
  const int tid = threadIdx.x, lane = tid & 63, wid = tid >> 6;
  const int p = (TT / 128 - 1) - blockIdx.x / (BB * HH);
  const int bh = blockIdx.x % (BB * HH);
  const uint16_t* qb = qkvh + (size_t)bh * (TT * 64);
  const uint16_t* kb = qkvh + QKREG + (size_t)bh * (TT * 64);
  const uint16_t* vb = qkvh + 2 * QKREG + (size_t)bh * ((size_t)64 * TT);
  const int l15 = lane & 15, lhi = lane >> 4;
  bf16x8 qf[2];
  {
    const uint16_t* qr = qb + (size_t)(p * 128 + wid * 16 + l15) * 64 + lhi * 8;
    qf[0] = *(const bf16x8*)qr;
    qf[1] = *(const bf16x8*)(qr + 32);
  }
  const int r0 = tid >> 3;
  const int cb0 = (tid & 7) * 16;
  const int ph0 = r0 * 128 + (cb0 ^ ((r0 & 7) << 4));

  uint4 kr0, vr0;
  kr0 = *(const uint4*)(kb + (size_t)r0 * 64 + cb0 / 2);
  vr0 = *(const uint4*)(vb + (size_t)r0 * TT + cb0 / 2);
  *(uint4*)((char*)Ks[0] + ph0) = kr0;
  *(uint4*)((char*)Vs[0] + ph0) = vr0;

  f32x4 oacc[4] = {};
  float mrun[4] = {-INFINITY, -INFINITY, -INFINITY, -INFINITY};
  float lrun[4] = {0.f, 0.f, 0.f, 0.f};
  char* pb = (char*)Ps[wid];
  const int jmax = 2 * p + 1;
  const int qgmin = p * 128 + wid * 16;

  for (int j = 0; j <= jmax; ++j) {
    const int cur = j & 1;
    const bool more = (j < jmax);
    __syncthreads();
    if (more) {
      const int jn = (j + 1) * 64;
      kr0 = *(const uint4*)(kb + (size_t)(jn + r0) * 64 + cb0 / 2);
      vr0 = *(const uint4*)(vb + (size_t)r0 * TT + jn + cb0 / 2);
    }
    const char* Kb = (const char*)Ks[cur];
    const char* Vb = (const char*)Vs[cur];
    f32x4 s4[4] = {};
    __builtin_amdgcn_s_setprio(1);
#pragma unroll
    for (int kk = 0; kk < 2; ++kk) {
      const int cbyte = kk * 64 + lhi * 16;
#pragma unroll
      for (int nt = 0; nt < 4; ++nt) {
        const int krow = nt * 16 + l15;
        const bf16x8 kf = *(const bf16x8*)(Kb + krow * 128 + (cbyte ^ ((krow & 7) << 4)));
        s4[nt] = mfma16(qf[kk], kf, s4[nt]);
      }
    }
    __builtin_amdgcn_s_setprio(0);
    const bool diag = (j * 64 + 63) > qgmin;
    float alpha[4];
#pragma unroll
    for (int r = 0; r < 4; ++r) {
      const int qg = qgmin + (lhi << 2) + r;
      float mx = -INFINITY;
#pragma unroll
      for (int nt = 0; nt < 4; ++nt) {
        float v = s4[nt][r] * 0.125f;
        if (diag && (j * 64 + nt * 16 + l15) > qg) v = -INFINITY;
        s4[nt][r] = v;
        mx = fmaxf(mx, v);
      }
#pragma unroll
      for (int m = 1; m < 16; m <<= 1) mx = fmaxf(mx, __shfl_xor(mx, m, 16));
      const float mnew = fmaxf(mrun[r], mx);
      alpha[r] = __expf(mrun[r] - mnew);
      float ps = 0.f;
#pragma unroll
      for (int nt = 0; nt < 4; ++nt) {
        const float pp = __expf(s4[nt][r] - mnew);
        s4[nt][r] = pp;
        ps += pp;
      }
#pragma unroll
      for (int m = 1; m < 16; m <<= 1) ps += __shfl_xor(ps, m, 16);
      lrun[r] = lrun[r] * alpha[r] + ps;
      mrun[r] = mnew;
    }
#pragma unroll
    for (int dt = 0; dt < 4; ++dt)
#pragma unroll
      for (int r = 0; r < 4; ++r) oacc[dt][r] *= alpha[r];
#pragma unroll
    for (int r = 0; r < 4; ++r) {
      const int prow = (lhi << 2) + r;
      const int swp = (prow & 7) << 4;
#pragma unroll
      for (int nt = 0; nt < 4; ++nt) {
        const int cb = (nt * 16 + l15) * 2;
        *(uint16_t*)(pb + prow * 128 + (cb ^ swp)) = f2b(s4[nt][r]);
      }
    }
    __builtin_amdgcn_s_setprio(1);
#pragma unroll
    for (int kk = 0; kk < 2; ++kk) {
      const int cbyte = kk * 64 + lhi * 16;
      const bf16x8 pf = *(const bf16x8*)(pb + l15 * 128 + (cbyte ^ ((l15 & 7) << 4)));
#pragma unroll
      for (int dt = 0; dt < 4; ++dt) {
        const int vrow = dt * 16 + l15;
        const bf16x8 vf = *(const bf16x8*)(Vb + vrow * 128 + (cbyte ^ ((vrow & 7) << 4)));
        oacc[dt] = mfma16(pf, vf, oacc[dt]);
      }
    }
    __builtin_amdgcn_s_setprio(0);
    if (more) {
      char* kn = (char*)Ks[cur ^ 1];
      char* vn = (char*)Vs[cur ^ 1];
      *(uint4*)(kn + ph0) = kr0;
      *(uint4*)(vn + ph0) = vr0;
    }
  }
#pragma unroll
  for (int dt = 0; dt < 4; ++dt) {
#pragma unroll
    for (int r = 0; r < 4; ++r) {
      const int q = p * 128 + wid * 16 + (lhi << 2) + r;
      const float v = oacc[dt][r] / lrun[r];
      ao[(size_t)((bh / HH) * TT + q) * CC + (bh % HH) * HDIM + dt * 16 + l15] = f2b(v);
    }
  }
}

extern "C" void kernel_launch(void* const* d_in, const int* in_sizes, int n_in,
                              void* d_out, int out_size, void* d_ws, size_t ws_size,
                              hipStream_t stream) {
  (void)in_sizes; (void)n_in; (void)out_size;
  const int*   idx  = (const int*)d_in[0];
  const float* tok  = (const float*)d_in[1];
  const float* pos  = (const float*)d_in[2];
  const float* Wqkv = (const float*)d_in[3];
  const float* Wpro = (const float*)d_in[4];
  const float* W1   = (const float*)d_in[5];
  const float* b1   = (const float*)d_in[6];
  const float* W2   = (const float*)d_in[7];
  const float* b2   = (const float*)d_in[8];
  const float* g1   = (const float*)d_in[9];
  const float* be1  = (const float*)d_in[10];
  const float* g2   = (const float*)d_in[11];
  const float* be2  = (const float*)d_in[12];
  const float* gf   = (const float*)d_in[13];
  const float* bfb  = (const float*)d_in[14];
  float* out = (float*)d_out;

  const size_t QS = (size_t)CC * 3 * CC;
  const size_t PS = (size_t)CC * CC;
  const size_t S1 = (size_t)CC * DFF;
  const size_t S2 = (size_t)DFF * CC;

  char* p = (char*)d_ws;
  uint16_t* x = (uint16_t*)p;      p += (size_t)MM * CC * 2;
  uint16_t* act = (uint16_t*)p;    p += (size_t)MM * CC * 2;
  uint16_t* big = (uint16_t*)p;    p += (size_t)MM * DFF * 2;
  uint16_t* tokb = (uint16_t*)p;   p += (size_t)VV * CC * 2;
  uint16_t* partb = (uint16_t*)p;  p += (size_t)2 * MM * CC * 2;
  char* pbase = p;
  uint16_t* wqA = (uint16_t*)p;    p += QS * LNUM * 2;
  uint16_t* wpA = (uint16_t*)p;    p += PS * LNUM * 2;
  uint16_t* w1A = (uint16_t*)p;    p += S1 * LNUM * 2;
  uint16_t* w2A = (uint16_t*)p;    p += S2 * LNUM * 2;
  const bool roomy2 = ws_size >= (size_t)(p - (char*)d_ws);
  if (!roomy2) {
    p = pbase;
    wqA = (uint16_t*)p; p += QS * 2;
    wpA = (uint16_t*)p; p += PS * 2;
    w1A = (uint16_t*)p; p += S1 * 2;
    w2A = (uint16_t*)p; p += S2 * 2;
  }

  cvt4_k<<<dim3((VV * CC / 4 + 255) / 256), 256, 0, stream>>>(tok, tokb, VV * CC / 4);
  embed_k<<<dim3(MM * (CC / 4) / 256), 256, 0, stream>>>(idx, tok, pos, x);
  ln_k<<<dim3(MM / 4), 256, 0, stream>>>(x, g1, be1, act);
  if (roomy2)
    tca_k<<<dim3(LNUM * 3456), 256, 0, stream>>>(Wqkv, Wpro, W1, W2, wqA, wpA, w1A, w2A);

  for (int l = 0; l < LNUM; ++l) {
    if (!roomy2)
      tca_k<<<dim3(3456), 256, 0, stream>>>(Wqkv + (size_t)l * QS, Wpro + (size_t)l * PS,
                                            W1 + (size_t)l * S1, W2 + (size_t)l * S2,
                                            wqA, wpA, w1A, w2A);
    const size_t lw = roomy2 ? (size_t)l : 0;
    gemm_k<5><<<dim3(MM / 128, 3 * CC / 128, 1), 256, 0, stream>>>(
        act, wqA + lw * QS, 3 * CC, CC, nullptr, big, nullptr);
    attn_k<<<dim3((TT / 128) * BB * HH), 512, 0, stream>>>(big, act);
    // proj: unsplit plain bf16 store (EPI8, z=1) -> lnrb NP=1
    gemm_k<8><<<dim3(MM / 128, CC / 128, 1), 256, 0, stream>>>(
        act, wpA + lw * PS, CC, CC, nullptr, partb, nullptr);
    lnrb_k<1, true><<<dim3(MM / 4), 256, 0, stream>>>(
        x, partb, g2 + (size_t)l * CC, be2 + (size_t)l * CC, act);
    gemm_k<2><<<dim3(MM / 128, DFF / 128, 1), 256, 0, stream>>>(
        act, w1A + lw * S1, DFF, CC, b1 + (size_t)l * DFF, big, nullptr);
    const float* ng = (l + 1 < LNUM) ? g1 + (size_t)(l + 1) * CC : gf;
    const float* nb = (l + 1 < LNUM) ? be1 + (size_t)(l + 1) * CC : bfb;
    gemm_k<8><<<dim3(MM / 128, CC / 128, 2), 256, 0, stream>>>(
        big, w2A + lw * S2, CC, DFF, b2 + (size_t)l * CC, partb, nullptr);
    if (l + 1 < LNUM)
      lnrb_k<2, true><<<dim3(MM / 4), 256, 0, stream>>>(x, partb, ng, nb, act);
    else
      lnrb_k<2, false><<<dim3(MM / 4), 256, 0, stream>>>(x, partb, ng, nb, act);
  }
  gemm_k<1><<<dim3(MM / 128, VV / 128, 1), 256, 0, stream>>>(
      act, tokb, VV, CC, nullptr, nullptr, out);
}

// Round 18
// 1462.070 us; speedup vs baseline: 1.1569x; 1.0106x over previous
//
#include <hip/hip_runtime.h>
#include <hip/hip_bf16.h>
#include <stdint.h>

#define LNUM 6
#define BB 8
#define TT 1024
#define CC 768
#define HH 12
#define HDIM 64
#define DFF 3072
#define VV 512
#define MM (BB*TT)
#define QKREG ((size_t)BB*HH*TT*64)

typedef __bf16 bf16x8 __attribute__((ext_vector_type(8)));
typedef float f32x4 __attribute__((ext_vector_type(4)));
typedef float f32x16 __attribute__((ext_vector_type(16)));

__device__ __forceinline__ uint16_t f2b(float f) {
  uint32_t u = __float_as_uint(f);
  u += 0x7FFFu + ((u >> 16) & 1u);
  return (uint16_t)(u >> 16);
}

__device__ __forceinline__ float b2f(uint16_t u) {
  return __uint_as_float((uint32_t)u << 16);
}

__device__ __forceinline__ void gld16(const uint16_t* g, uint16_t* l) {
  __builtin_amdgcn_global_load_lds(
      (const __attribute__((address_space(1))) uint32_t*)g,
      (__attribute__((address_space(3))) uint32_t*)l, 16, 0, 0);
}

__device__ __forceinline__ f32x4 mfma16(bf16x8 a, bf16x8 b, f32x4 c) {
  return __builtin_amdgcn_mfma_f32_16x16x32_bf16(a, b, c, 0, 0, 0);
}

__device__ __forceinline__ f32x16 mfma32(bf16x8 a, bf16x8 b, f32x16 c) {
  return __builtin_amdgcn_mfma_f32_32x32x16_bf16(a, b, c, 0, 0, 0);
}

// ---------------- convert f32 -> bf16 ----------------
__global__ __launch_bounds__(256) void cvt4_k(const float* __restrict__ in,
                                              uint16_t* __restrict__ out, int n4) {
  const int gid = blockIdx.x * 256 + threadIdx.x;
  if (gid >= n4) return;
  const float4 v = ((const float4*)in)[gid];
  ushort4 w; w.x = f2b(v.x); w.y = f2b(v.y); w.z = f2b(v.z); w.w = f2b(v.w);
  ((ushort4*)out)[gid] = w;
}

// ---------------- embedding: x(bf16) = tok_emb[idx] + pos_emb ----------------
__global__ __launch_bounds__(256) void embed_k(const int* __restrict__ idx,
                                               const float* __restrict__ tok,
                                               const float* __restrict__ pos,
                                               uint16_t* __restrict__ x) {
  const int gid = blockIdx.x * 256 + threadIdx.x;
  const int row = gid / (CC / 4), c4 = gid % (CC / 4);
  const int t = row & (TT - 1);
  const int tkn = idx[row];
  const float4 a = ((const float4*)(tok + (size_t)tkn * CC))[c4];
  const float4 q = ((const float4*)(pos + (size_t)t * CC))[c4];
  ushort4 w;
  w.x = f2b(a.x + q.x); w.y = f2b(a.y + q.y);
  w.z = f2b(a.z + q.z); w.w = f2b(a.w + q.w);
  ((ushort4*)(x + (size_t)row * CC))[c4] = w;
}

// ---------------- layernorm: bf16 x in -> bf16 out ----------------
__global__ __launch_bounds__(256) void ln_k(const uint16_t* __restrict__ x,
                                            const float* __restrict__ gamma,
                                            const float* __restrict__ beta,
                                            uint16_t* __restrict__ o) {
  const int lane = threadIdx.x & 63, wid = threadIdx.x >> 6;
  const int row = blockIdx.x * 4 + wid;
  const ushort4* xr = (const ushort4*)(x + (size_t)row * CC);
  float4 v[3]; float s = 0.f, sq = 0.f;
#pragma unroll
  for (int i = 0; i < 3; ++i) {
    const ushort4 u = xr[lane + i * 64];
    v[i] = make_float4(b2f(u.x), b2f(u.y), b2f(u.z), b2f(u.w));
    s += v[i].x + v[i].y + v[i].z + v[i].w;
    sq += v[i].x * v[i].x + v[i].y * v[i].y + v[i].z * v[i].z + v[i].w * v[i].w;
  }
#pragma unroll
  for (int m = 1; m < 64; m <<= 1) { s += __shfl_xor(s, m, 64); sq += __shfl_xor(sq, m, 64); }
  const float mu = s * (1.f / 768.f);
  const float rstd = rsqrtf(sq * (1.f / 768.f) - mu * mu + 1e-5f);
  ushort4* orow = (ushort4*)(o + (size_t)row * CC);
#pragma unroll
  for (int i = 0; i < 3; ++i) {
    const int c4 = lane + i * 64;
    const float4 gg = ((const float4*)gamma)[c4];
    const float4 bb = ((const float4*)beta)[c4];
    ushort4 w;
    w.x = f2b((v[i].x - mu) * rstd * gg.x + bb.x);
    w.y = f2b((v[i].y - mu) * rstd * gg.y + bb.y);
    w.z = f2b((v[i].z - mu) * rstd * gg.z + bb.z);
    w.w = f2b((v[i].w - mu) * rstd * gg.w + bb.w);
    orow[c4] = w;
  }
}

// --- layernorm + NP bf16-partial reduce: x(bf16) += sum(p_j); o = LN(x) ---
template <int NP, bool WX>
__global__ __launch_bounds__(256) void lnrb_k(uint16_t* __restrict__ x,
                                              const uint16_t* __restrict__ pp,
                                              const float* __restrict__ gamma,
                                              const float* __restrict__ beta,
                                              uint16_t* __restrict__ o) {
  const int lane = threadIdx.x & 63, wid = threadIdx.x >> 6;
  const int row = blockIdx.x * 4 + wid;
  ushort4* xr = (ushort4*)(x + (size_t)row * CC);
  float4 v[3]; float s = 0.f, sq = 0.f;
#pragma unroll
  for (int i = 0; i < 3; ++i) {
    const int c4 = lane + i * 64;
    const ushort4 u = xr[c4];
    float4 a = make_float4(b2f(u.x), b2f(u.y), b2f(u.z), b2f(u.w));
#pragma unroll
    for (int j = 0; j < NP; ++j) {
      const ushort4 q =
          ((const ushort4*)(pp + (size_t)j * MM * CC + (size_t)row * CC))[c4];
      a.x += b2f(q.x); a.y += b2f(q.y); a.z += b2f(q.z); a.w += b2f(q.w);
    }
    if (WX) {
      ushort4 w;
      w.x = f2b(a.x); w.y = f2b(a.y); w.z = f2b(a.z); w.w = f2b(a.w);
      xr[c4] = w;
    }
    v[i] = a;
    s += a.x + a.y + a.z + a.w;
    sq += a.x * a.x + a.y * a.y + a.z * a.z + a.w * a.w;
  }
#pragma unroll
  for (int m = 1; m < 64; m <<= 1) { s += __shfl_xor(s, m, 64); sq += __shfl_xor(sq, m, 64); }
  const float mu = s * (1.f / 768.f);
  const float rstd = rsqrtf(sq * (1.f / 768.f) - mu * mu + 1e-5f);
  ushort4* orow = (ushort4*)(o + (size_t)row * CC);
#pragma unroll
  for (int i = 0; i < 3; ++i) {
    const int c4 = lane + i * 64;
    const float4 gg = ((const float4*)gamma)[c4];
    const float4 bb = ((const float4*)beta)[c4];
    ushort4 w;
    w.x = f2b((v[i].x - mu) * rstd * gg.x + bb.x);
    w.y = f2b((v[i].y - mu) * rstd * gg.y + bb.y);
    w.z = f2b((v[i].z - mu) * rstd * gg.z + bb.z);
    w.w = f2b((v[i].w - mu) * rstd * gg.w + bb.w);
    orow[c4] = w;
  }
}

// ------- all-weights transpose+convert v2: 64(k)x32(n) tiles, 128B writes -------
__global__ __launch_bounds__(256) void tca_k(const float* __restrict__ Wq,
                                             const float* __restrict__ Wp,
                                             const float* __restrict__ W1p,
                                             const float* __restrict__ W2p,
                                             uint16_t* __restrict__ dq,
                                             uint16_t* __restrict__ dp,
                                             uint16_t* __restrict__ d1,
                                             uint16_t* __restrict__ d2) {
  __shared__ float tile[64][33];
  const int b = blockIdx.x;
  const int l = b / 3456;
  int r = b - l * 3456;
  const float* src; uint16_t* dst; int K, N, kt, nt;
  if (r < 864) {
    K = CC; N = 3 * CC;
    src = Wq + (size_t)l * CC * 3 * CC; dst = dq + (size_t)l * CC * 3 * CC;
    kt = r / 72; nt = r % 72;
  } else if (r < 1152) {
    r -= 864; K = CC; N = CC;
    src = Wp + (size_t)l * CC * CC; dst = dp + (size_t)l * CC * CC;
    kt = r / 24; nt = r % 24;
  } else if (r < 2304) {
    r -= 1152; K = CC; N = DFF;
    src = W1p + (size_t)l * CC * DFF; dst = d1 + (size_t)l * CC * DFF;
    kt = r / 96; nt = r % 96;
  } else {
    r -= 2304; K = DFF; N = CC;
    src = W2p + (size_t)l * DFF * CC; dst = d2 + (size_t)l * DFF * CC;
    kt = r / 24; nt = r % 24;
  }
  const int kb = kt * 64, nb = nt * 32;
  const int tx = threadIdx.x & 31, ty = threadIdx.x >> 5;
#pragma unroll
  for (int i = 0; i < 64; i += 8)
    tile[ty + i][tx] = src[(size_t)(kb + ty + i) * N + nb + tx];
  __syncthreads();
#pragma unroll
  for (int i = 0; i < 32; i += 8) {
    const int n = ty + i;
    const int k2 = tx * 2;
    const uint32_t w = (uint32_t)f2b(tile[k2][n]) | ((uint32_t)f2b(tile[k2 + 1][n]) << 16);
    *(uint32_t*)(dst + (size_t)(nb + n) * K + kb + k2) = w;
  }
}

// ---- 128x128 GEMM, BK=64, chunk-swizzled LDS, 32x32x16 MFMA (m97 structure) ----
// Per wave: 64x64 output = 2x2 frags of 32x32; K=64 tile = 4 ksteps of 16.
// 16 mfma32/tile (vs 32 mfma16) at the faster 32x32 pipe rate; LDS traffic same.
// Frag read: lane l -> row base+(l&31), chunk (kt*2+(l>>5)) ^ (row&7) (same
// involution as staging; per 16-lane quarter: 2 rows/chunk = conflict-free).
// C/D map (m74/m101): col = lane&31, row = (reg&3) + 8*(reg>>2) + 4*(lane>>5).
// EPI: 1 = f32 store; 2 = bias+GELU -> bf16; 5 = qkv split; 8 = bf16 partials (+bias kp0)
template <int EPI>
__global__ __launch_bounds__(256) void gemm_k(const uint16_t* __restrict__ A,
                                              const uint16_t* __restrict__ Bt,
                                              int N, int K,
                                              const float* __restrict__ bias,
                                              uint16_t* __restrict__ outb,
                                              float* __restrict__ outf) {
  __shared__ __align__(16) uint16_t As[128 * 64];
  __shared__ __align__(16) uint16_t Bs[128 * 64];
  const int tid = threadIdx.x;
  const int lane = tid & 63, wid = tid >> 6;
  const int wm = wid >> 1, wn = wid & 1;
  const int bm = blockIdx.x * 128, bn = blockIdx.y * 128;
  const int kp = blockIdx.z;
  const int Ksub = K / (int)gridDim.z;
  const int k0b = kp * Ksub;
  const int nkt = Ksub >> 6;
  const int srow = tid >> 3;
  const int swz = (tid & 7) ^ (srow & 7);
  const uint16_t* gA0 = A + (size_t)(bm + srow) * K + k0b + swz * 8;
  const uint16_t* gB0 = Bt + (size_t)(bn + srow) * K + k0b + swz * 8;
  const size_t qs = (size_t)32 * K;
  const int l31 = lane & 31, lhi = lane >> 5;
  // frag LDS byte offsets: [frag 32-block][kstep]
  int aof[2][4], bof[2][4];
#pragma unroll
  for (int f = 0; f < 2; ++f)
#pragma unroll
    for (int kt = 0; kt < 4; ++kt) {
      const int ch = ((kt * 2 + lhi) ^ (l31 & 7)) * 16;
      aof[f][kt] = (wm * 64 + f * 32 + l31) * 128 + ch;
      bof[f][kt] = (wn * 64 + f * 32 + l31) * 128 + ch;
    }
  f32x16 acc[2][2] = {};
  for (int t = 0; t < nkt; ++t) {
    const int ko = t * 64;
#pragma unroll
    for (int q = 0; q < 4; ++q) {
      gld16(gA0 + q * qs + ko, &As[q * 2048 + tid * 8]);
      gld16(gB0 + q * qs + ko, &Bs[q * 2048 + tid * 8]);
    }
    __syncthreads();
    const char* Ab = (const char*)As;
    const char* Bb = (const char*)Bs;
#pragma unroll
    for (int kt = 0; kt < 4; ++kt) {
      bf16x8 a0 = *(const bf16x8*)(Ab + aof[0][kt]);
      bf16x8 a1 = *(const bf16x8*)(Ab + aof[1][kt]);
      bf16x8 b0 = *(const bf16x8*)(Bb + bof[0][kt]);
      bf16x8 b1 = *(const bf16x8*)(Bb + bof[1][kt]);
      acc[0][0] = mfma32(a0, b0, acc[0][0]);
      acc[0][1] = mfma32(a0, b1, acc[0][1]);
      acc[1][0] = mfma32(a1, b0, acc[1][0]);
      acc[1][1] = mfma32(a1, b1, acc[1][1]);
    }
    __syncthreads();
  }
  // ---- epilogue: row = (reg&3) + 8*(reg>>2) + 4*lhi, col = l31 ----
#pragma unroll
  for (int fi = 0; fi < 2; ++fi) {
#pragma unroll
    for (int fj = 0; fj < 2; ++fj) {
      const int col = bn + wn * 64 + fj * 32 + l31;
#pragma unroll
      for (int q = 0; q < 4; ++q) {
        const int m0 = bm + wm * 64 + fi * 32 + q * 8 + lhi * 4;
        if constexpr (EPI == 5) {
          const int sec = col / CC;
          const int rn = col - sec * CC;
          const int hh = rn >> 6, d = rn & 63;
          const int b = m0 >> 10, t0 = m0 & 1023;
          if (sec == 2) {
            ushort4 w;
            w.x = f2b(acc[fi][fj][q * 4 + 0]); w.y = f2b(acc[fi][fj][q * 4 + 1]);
            w.z = f2b(acc[fi][fj][q * 4 + 2]); w.w = f2b(acc[fi][fj][q * 4 + 3]);
            *(ushort4*)(outb + 2 * QKREG + ((size_t)(b * HH + hh) * 64 + d) * TT + t0) = w;
          } else {
            uint16_t* dst = outb + (size_t)sec * QKREG + ((size_t)(b * HH + hh) * TT + t0) * 64 + d;
#pragma unroll
            for (int rr = 0; rr < 4; ++rr) dst[(size_t)rr * 64] = f2b(acc[fi][fj][q * 4 + rr]);
          }
        } else if constexpr (EPI == 8) {
          uint16_t* pdst = outb + (size_t)kp * ((size_t)MM * N);
          const float bb = (kp == 0 && bias) ? bias[col] : 0.f;
#pragma unroll
          for (int rr = 0; rr < 4; ++rr)
            pdst[(size_t)(m0 + rr) * N + col] = f2b(acc[fi][fj][q * 4 + rr] + bb);
        } else {
#pragma unroll
          for (int rr = 0; rr < 4; ++rr) {
            const size_t o = (size_t)(m0 + rr) * N + col;
            const float v = acc[fi][fj][q * 4 + rr];
            if constexpr (EPI == 1) {
              outf[o] = v;
            } else if constexpr (EPI == 2) {
              float tt = v + bias[col];
              tt = 0.5f * tt * (1.0f + erff(tt * 0.70710678118654752f));
              outb[o] = f2b(tt);
            }
          }
        }
      }
    }
  }
}

// ---- fused causal flash attention: QBLK=128 (8 waves), dbuf K/V, 1 barrier/tile ----
__global__ __launch_bounds__(512) void attn_k(const uint16_t* __restrict__ qkvh,
                                              uint16_t* __restrict__ ao) {
  __shared__ __align__(16) uint16_t Ks[2][64 * 64], Vs[2][64 * 64];
  __shared__ __align__(16) uint16_t Ps[8][16 * 64];
  const int tid = threadIdx.x, lane = tid & 63, wid = tid >> 6;
  const int p = (TT / 128 - 1) - blockIdx.x / (BB * HH);
  const int bh = blockIdx.x % (BB * HH);
  const uint16_t* qb = qkvh + (size_t)bh * (TT * 64);
  const uint16_t* kb = qkvh + QKREG + (size_t)bh * (TT * 64);
  const uint16_t* vb = qkvh + 2 * QKREG + (size_t)bh * ((size_t)64 * TT);
  const int l15 = lane & 15, lhi = lane >> 4;
  bf16x8 qf[2];
  {
    const uint16_t* qr = qb + (size_t)(p * 128 + wid * 16 + l15) * 64 + lhi * 8;
    qf[0] = *(const bf16x8*)qr;
    qf[1] = *(const bf16x8*)(qr + 32);
  }
  const int r0 = tid >> 3;
  const int cb0 = (tid & 7) * 16;
  const int ph0 = r0 * 128 + (cb0 ^ ((r0 & 7) << 4));

  uint4 kr0, vr0;
  kr0 = *(const uint4*)(kb + (size_t)r0 * 64 + cb0 / 2);
  vr0 = *(const uint4*)(vb + (size_t)r0 * TT + cb0 / 2);
  *(uint4*)((char*)Ks[0] + ph0) = kr0;
  *(uint4*)((char*)Vs[0] + ph0) = vr0;

  f32x4 oacc[4] = {};
  float mrun[4] = {-INFINITY, -INFINITY, -INFINITY, -INFINITY};
  float lrun[4] = {0.f, 0.f, 0.f, 0.f};
  char* pb = (char*)Ps[wid];
  const int jmax = 2 * p + 1;
  const int qgmin = p * 128 + wid * 16;

  for (int j = 0; j <= jmax; ++j) {
    const int cur = j & 1;
    const bool more = (j < jmax);
    __syncthreads();
    if (more) {
      const int jn = (j + 1) * 64;
      kr0 = *(const uint4*)(kb + (size_t)(jn + r0) * 64 + cb0 / 2);
      vr0 = *(const uint4*)(vb + (size_t)r0 * TT + jn + cb0 / 2);
    }
    const char* Kb = (const char*)Ks[cur];
    const char* Vb = (const char*)Vs[cur];
    f32x4 s4[4] = {};
    __builtin_amdgcn_s_setprio(1);
#pragma unroll
    for (int kk = 0; kk < 2; ++kk) {
      const int cbyte = kk * 64 + lhi * 16;
#pragma unroll
      for (int nt = 0; nt < 4; ++nt) {
        const int krow = nt * 16 + l15;
        const bf16x8 kf = *(const bf16x8*)(Kb + krow * 128 + (cbyte ^ ((krow & 7) << 4)));
        s4[nt] = mfma16(qf[kk], kf, s4[nt]);
      }
    }
    __builtin_amdgcn_s_setprio(0);
    const bool diag = (j * 64 + 63) > qgmin;
    float alpha[4];
#pragma unroll
    for (int r = 0; r < 4; ++r) {
      const int qg = qgmin + (lhi << 2) + r;
      float mx = -INFINITY;
#pragma unroll
      for (int nt = 0; nt < 4; ++nt) {
        float v = s4[nt][r] * 0.125f;
        if (diag && (j * 64 + nt * 16 + l15) > qg) v = -INFINITY;
        s4[nt][r] = v;
        mx = fmaxf(mx, v);
      }
#pragma unroll
      for (int m = 1; m < 16; m <<= 1) mx = fmaxf(mx, __shfl_xor(mx, m, 16));
      const float mnew = fmaxf(mrun[r], mx);
      alpha[r] = __expf(mrun[r] - mnew);
      float ps = 0.f;
#pragma unroll
      for (int nt = 0; nt < 4; ++nt) {
        const float pp = __expf(s4[nt][r] - mnew);
        s4[nt][r] = pp;
        ps += pp;
      }
#pragma unroll
      for (int m = 1; m < 16; m <<= 1) ps += __shfl_xor(ps, m, 16);
      lrun[r] = lrun[r] * alpha[r] + ps;
      mrun[r] = mnew;
    }
#pragma unroll
    for (int dt = 0; dt < 4; ++dt)
#pragma unroll
      for (int r = 0; r < 4; ++r) oacc[dt][r] *= alpha[r];
#pragma unroll
    for (int r = 0; r < 4; ++r) {
      const int prow = (lhi << 2) + r;
      const int swp = (prow & 7) << 4;
#pragma unroll
      for (int nt = 0; nt < 4; ++nt) {
        const int cb = (nt * 16 + l15) * 2;
        *(uint16_t*)(pb + prow * 128 + (cb ^ swp)) = f2b(s4[nt][r]);
      }
    }
    __builtin_amdgcn_s_setprio(1);
#pragma unroll
    for (int kk = 0; kk < 2; ++kk) {
      const int cbyte = kk * 64 + lhi * 16;
      const bf16x8 pf = *(const bf16x8*)(pb + l15 * 128 + (cbyte ^ ((l15 & 7) << 4)));
#pragma unroll
      for (int dt = 0; dt < 4; ++dt) {
        const int vrow = dt * 16 + l15;
        const bf16x8 vf = *(const bf16x8*)(Vb + vrow * 128 + (cbyte ^ ((vrow & 7) << 4)));
        oacc[dt] = mfma16(pf, vf, oacc[dt]);
      }
    }
    __builtin_amdgcn_s_setprio(0);
    if (more) {
      char* kn = (char*)Ks[cur ^ 1];
      char* vn = (char*)Vs[cur ^ 1];
      *(uint4*)(kn + ph0) = kr0;
      *(uint4*)(vn + ph0) = vr0;
    }
  }
#pragma unroll
  for (int dt = 0; dt < 4; ++dt) {
#pragma unroll
    for (int r = 0; r < 4; ++r) {
      const int q = p * 128 + wid * 16 + (lhi << 2) + r;
      const float v = oacc[dt][r] / lrun[r];
      ao[(size_t)((bh / HH) * TT + q) * CC + (bh % HH) * HDIM + dt * 16 + l15] = f2b(v);
    }
  }
}

extern "C" void kernel_launch(void* const* d_in, const int* in_sizes, int n_in,
                              void* d_out, int out_size, void* d_ws, size_t ws_size,
                              hipStream_t stream) {
  (void)in_sizes; (void)n_in; (void)out_size;
  const int*   idx  = (const int*)d_in[0];
  const float* tok  = (const float*)d_in[1];
  const float* pos  = (const float*)d_in[2];
  const float* Wqkv = (const float*)d_in[3];
  const float* Wpro = (const float*)d_in[4];
  const float* W1   = (const float*)d_in[5];
  const float* b1   = (const float*)d_in[6];
  const float* W2   = (const float*)d_in[7];
  const float* b2   = (const float*)d_in[8];
  const float* g1   = (const float*)d_in[9];
  const float* be1  = (const float*)d_in[10];
  const float* g2   = (const float*)d_in[11];
  const float* be2  = (const float*)d_in[12];
  const float* gf   = (const float*)d_in[13];
  const float* bfb  = (const float*)d_in[14];
  float* out = (float*)d_out;

  const size_t QS = (size_t)CC * 3 * CC;
  const size_t PS = (size_t)CC * CC;
  const size_t S1 = (size_t)CC * DFF;
  const size_t S2 = (size_t)DFF * CC;

  char* p = (char*)d_ws;
  uint16_t* x = (uint16_t*)p;      p += (size_t)MM * CC * 2;
  uint16_t* act = (uint16_t*)p;    p += (size_t)MM * CC * 2;
  uint16_t* big = (uint16_t*)p;    p += (size_t)MM * DFF * 2;
  uint16_t* tokb = (uint16_t*)p;   p += (size_t)VV * CC * 2;
  uint16_t* partb = (uint16_t*)p;  p += (size_t)2 * MM * CC * 2;
  char* pbase = p;
  uint16_t* wqA = (uint16_t*)p;    p += QS * LNUM * 2;
  uint16_t* wpA = (uint16_t*)p;    p += PS * LNUM * 2;
  uint16_t* w1A = (uint16_t*)p;    p += S1 * LNUM * 2;
  uint16_t* w2A = (uint16_t*)p;    p += S2 * LNUM * 2;
  const bool roomy2 = ws_size >= (size_t)(p - (char*)d_ws);
  if (!roomy2) {
    p = pbase;
    wqA = (uint16_t*)p; p += QS * 2;
    wpA = (uint16_t*)p; p += PS * 2;
    w1A = (uint16_t*)p; p += S1 * 2;
    w2A = (uint16_t*)p; p += S2 * 2;
  }

  cvt4_k<<<dim3((VV * CC / 4 + 255) / 256), 256, 0, stream>>>(tok, tokb, VV * CC / 4);
  embed_k<<<dim3(MM * (CC / 4) / 256), 256, 0, stream>>>(idx, tok, pos, x);
  ln_k<<<dim3(MM / 4), 256, 0, stream>>>(x, g1, be1, act);
  if (roomy2)
    tca_k<<<dim3(LNUM * 3456), 256, 0, stream>>>(Wqkv, Wpro, W1, W2, wqA, wpA, w1A, w2A);

  for (int l = 0; l < LNUM; ++l) {
    if (!roomy2)
      tca_k<<<dim3(3456), 256, 0, stream>>>(Wqkv + (size_t)l * QS, Wpro + (size_t)l * PS,
                                            W1 + (size_t)l * S1, W2 + (size_t)l * S2,
                                            wqA, wpA, w1A, w2A);
    const size_t lw = roomy2 ? (size_t)l : 0;
    gemm_k<5><<<dim3(MM / 128, 3 * CC / 128, 1), 256, 0, stream>>>(
        act, wqA + lw * QS, 3 * CC, CC, nullptr, big, nullptr);
    attn_k<<<dim3((TT / 128) * BB * HH), 512, 0, stream>>>(big, act);
    gemm_k<8><<<dim3(MM / 128, CC / 128, 1), 256, 0, stream>>>(
        act, wpA + lw * PS, CC, CC, nullptr, partb, nullptr);
    lnrb_k<1, true><<<dim3(MM / 4), 256, 0, stream>>>(
        x, partb, g2 + (size_t)l * CC, be2 + (size_t)l * CC, act);
    gemm_k<2><<<dim3(MM / 128, DFF / 128, 1), 256, 0, stream>>>(
        act, w1A + lw * S1, DFF, CC, b1 + (size_t)l * DFF, big, nullptr);
    const float* ng = (l + 1 < LNUM) ? g1 + (size_t)(l + 1) * CC : gf;
    const float* nb = (l + 1 < LNUM) ? be1 + (size_t)(l + 1) * CC : bfb;
    gemm_k<8><<<dim3(MM / 128, CC / 128, 2), 256, 0, stream>>>(
        big, w2A + lw * S2, CC, DFF, b2 + (size_t)l * CC, partb, nullptr);
    if (l + 1 < LNUM)
      lnrb_k<2, true><<<dim3(MM / 4), 256, 0, stream>>>(x, partb, ng, nb, act);
    else
      lnrb_k<2, false><<<dim3(MM / 4), 256, 0, stream>>>(x, partb, ng, nb, act);
  }
  gemm_k<1><<<dim3(MM / 128, VV / 128, 1), 256, 0, stream>>>(
      act, tokb, VV, CC, nullptr, nullptr, out);
}